// Round 1
// 1734.747 us; speedup vs baseline: 2.4970x; 2.4970x over previous
//
#include <hip/hip_runtime.h>
#include <hip/hip_bf16.h>
#include <stdint.h>

// Problem constants (fixed by setup_inputs)
constexpr int NH   = 32;            // query heads
constexpr int NKVH = 8;             // kv heads
constexpr int HD   = 128;           // head dim
constexpr int DM   = 4096;          // model dim (K of the GEMM)
constexpr int B    = 2;
constexpr int S    = 1024;
constexpr int T    = B * S;         // 2048
constexpr int QKVN = (NH + 2 * NKVH) * HD;  // 6144
constexpr int KOFF = NH * HD;               // 4096 (k section)
constexpr int VOFF = (NH + NKVH) * HD;      // 5120 (v section)

typedef float floatx4 __attribute__((ext_vector_type(4)));
typedef floatx4 floatx4_a __attribute__((may_alias));
typedef __bf16 bf16x8 __attribute__((ext_vector_type(8)));
typedef bf16x8 bf16x8_a __attribute__((may_alias));
typedef __bf16 bf16_a __attribute__((may_alias));

// ---------------------------------------------------------------------------
// 1) GEMM: qkv = hidden @ w_qkv, fp32 in, fp32 out. LDS-tiled, BM=BN=64,
//    BK=16; 256 threads; 4x4 micro-tile each. (Unchanged this round; next
//    round: bf16 MFMA m97-structure once fragment layouts are field-proven
//    by the attention kernel below.)
// ---------------------------------------------------------------------------
__global__ __launch_bounds__(256) void gemm_naive(
    const float* __restrict__ A,   // T x DM
    const float* __restrict__ W,   // DM x QKVN
    float* __restrict__ C) {       // T x QKVN  (fp32)
  __shared__ float As[16][65];  // [k][m], padded
  __shared__ float Bs[16][64];  // [k][n]
  const int tid = threadIdx.x;
  const int tx = tid & 15, ty = tid >> 4;
  const int m0 = blockIdx.y * 64, n0 = blockIdx.x * 64;

  const int sm = tid >> 2, sk4 = (tid & 3) * 4;   // A staging
  const int bk = tid >> 4, bn4 = (tid & 15) * 4;  // W staging

  float acc[4][4];
#pragma unroll
  for (int i = 0; i < 4; ++i)
#pragma unroll
    for (int j = 0; j < 4; ++j) acc[i][j] = 0.f;

  for (int kk = 0; kk < DM; kk += 16) {
    __syncthreads();
    floatx4 va = *(const floatx4_a*)(A + (size_t)(m0 + sm) * DM + kk + sk4);
#pragma unroll
    for (int e = 0; e < 4; ++e) As[sk4 + e][sm] = va[e];
    floatx4 vb = *(const floatx4_a*)(W + (size_t)(kk + bk) * QKVN + n0 + bn4);
    *(floatx4*)&Bs[bk][bn4] = vb;
    __syncthreads();
#pragma unroll
    for (int k = 0; k < 16; ++k) {
      float a[4], b[4];
#pragma unroll
      for (int e = 0; e < 4; ++e) a[e] = As[k][ty * 4 + e];
#pragma unroll
      for (int e = 0; e < 4; ++e) b[e] = Bs[k][tx * 4 + e];
#pragma unroll
      for (int i = 0; i < 4; ++i)
#pragma unroll
        for (int j = 0; j < 4; ++j) acc[i][j] += a[i] * b[j];
    }
  }
#pragma unroll
  for (int i = 0; i < 4; ++i)
#pragma unroll
    for (int j = 0; j < 4; ++j)
      C[(size_t)(m0 + ty * 4 + i) * QKVN + n0 + tx * 4 + j] = acc[i][j];
}

// ---------------------------------------------------------------------------
// 2) RoPE in-place on q and k sections of qkv (fp32). Unchanged.
// ---------------------------------------------------------------------------
__global__ __launch_bounds__(256) void rope_kernel(
    float* __restrict__ qkv, const float* __restrict__ cs,
    const float* __restrict__ sn) {
  const int idx = blockIdx.x * 256 + threadIdx.x;
  const int d = idx & 63;
  const int tmp = idx >> 6;
  const int head = tmp % (NH + NKVH);
  const int tt = tmp / (NH + NKVH);
  float* row = qkv + (size_t)tt * QKVN + head * HD;
  const float c = cs[tt * HD + d];
  const float s = sn[tt * HD + d];
  const float x1 = row[d];
  const float x2 = row[d + 64];
  row[d] = x1 * c - x2 * s;
  row[d + 64] = x2 * c + x1 * s;
}

// ---------------------------------------------------------------------------
// 3) Flash attention, bf16 MFMA (16x16x32), fp32 softmax/accum.
//    Block = (b, kvh, 16-row q-block); 4 waves = the 4 q-heads sharing K/V.
//    Per 32-key tile: stage K[32][128] + V^T[128][32] bf16 in swizzled LDS,
//    QK^T = 8 MFMA, online softmax in-register (rows in 16-lane groups per
//    verified C/D layout col=lane&15,row=(lane>>4)*4+reg), P via 1KB/wave
//    LDS to A-layout, PV = 8 MFMA. Swizzles: K row stride 256B -> XOR bits
//    4-6 ((row&7)<<4); P/V^T row stride 64B -> only bits 4-5 may be XORed
//    (bijectivity!), use ((row>>1)&3)<<4 / ((d>>2)&3)<<4.
// ---------------------------------------------------------------------------
__global__ __launch_bounds__(256) void attn_mfma(
    const float* __restrict__ qkv, float* __restrict__ out) {
  __shared__ __align__(16) char Ksh[32 * 128 * 2];  // swizzled [key][d] bf16
  __shared__ __align__(16) char Vsh[128 * 32 * 2];  // swizzled V^T [d][key]
  __shared__ __align__(16) char Psh[4][16 * 32 * 2];  // per-wave P [q][key]

  const int tid = threadIdx.x;
  const int lane = tid & 63, wave = tid >> 6;
  const int bid = (int)blockIdx.x;
  const int qb = bid & 63;          // 64 q-blocks of 16 rows
  const int kvh = (bid >> 6) & 7;
  const int b = bid >> 9;
  const int q0 = qb * 16;
  const int h = kvh * 4 + wave;     // head for this wave (h>>2 == kvh)
  const int NT = (q0 + 47) >> 5;    // number of 32-key tiles (causal)
  const float scale = 0.08838834764831845f;

  const int l15 = lane & 15, g = lane >> 4;

  // --- Q A-fragments, pre-scaled by 1/sqrt(HD), held in registers.
  // A layout: row m = lane&15 (q-row), k-slot = (lane>>4)*8 + e (d within
  // 32-chunk). Any consistent lane->k bijection contracts correctly as long
  // as B uses the same one.
  bf16x8 af[4];
  {
    const float* qr = qkv + (size_t)(b * S + q0 + l15) * QKVN + h * HD;
#pragma unroll
    for (int c = 0; c < 4; ++c) {
      const int d0 = c * 32 + g * 8;
      floatx4 f0 = *(const floatx4_a*)(qr + d0);
      floatx4 f1 = *(const floatx4_a*)(qr + d0 + 4);
      bf16x8 a;
#pragma unroll
      for (int e = 0; e < 4; ++e) {
        a[e] = (__bf16)(f0[e] * scale);
        a[e + 4] = (__bf16)(f1[e] * scale);
      }
      af[c] = a;
    }
  }

  floatx4 oacc[8];
#pragma unroll
  for (int i = 0; i < 8; ++i) oacc[i] = (floatx4){0.f, 0.f, 0.f, 0.f};
  float mrow[4], lrow[4], alpha[4];
#pragma unroll
  for (int i = 0; i < 4; ++i) {
    mrow[i] = -__builtin_inff();
    lrow[i] = 0.f;
  }

  // Staging assignments (256 threads)
  const int krow = tid >> 3, kdb = (tid & 7) * 16;     // K: row, d-chunk
  const int vk = tid & 31, vdb = (tid >> 5) * 16;      // V: key, d-chunk
  const float* kbaseg = qkv + (size_t)(b * S) * QKVN + KOFF + kvh * HD;
  const float* vbaseg = qkv + (size_t)(b * S) * QKVN + VOFF + kvh * HD;
  char* pb = (char*)Psh[wave];

  for (int kt = 0; kt < NT; ++kt) {
    const int kb = kt * 32;
    __syncthreads();  // previous tile's LDS reads done everywhere
    // ---- stage K tile: [32][128] fp32 -> bf16, swizzled
    {
      const float* src = kbaseg + (size_t)(kb + krow) * QKVN + kdb;
      floatx4 v0 = *(const floatx4_a*)(src);
      floatx4 v1 = *(const floatx4_a*)(src + 4);
      floatx4 v2 = *(const floatx4_a*)(src + 8);
      floatx4 v3 = *(const floatx4_a*)(src + 12);
      bf16x8 p0, p1;
#pragma unroll
      for (int e = 0; e < 4; ++e) {
        p0[e] = (__bf16)v0[e];
        p0[e + 4] = (__bf16)v1[e];
        p1[e] = (__bf16)v2[e];
        p1[e + 4] = (__bf16)v3[e];
      }
      const int swz = (krow & 7) << 4;
      const int base = krow * 256 + kdb * 2;
      *(bf16x8_a*)(Ksh + ((base) ^ swz)) = p0;
      *(bf16x8_a*)(Ksh + ((base + 16) ^ swz)) = p1;
    }
    // ---- stage V tile transposed: V^T[d][key] bf16, swizzled
    {
      const float* src = vbaseg + (size_t)(kb + vk) * QKVN + vdb;
#pragma unroll
      for (int q4 = 0; q4 < 4; ++q4) {
        floatx4 v = *(const floatx4_a*)(src + q4 * 4);
#pragma unroll
        for (int e = 0; e < 4; ++e) {
          const int d = vdb + q4 * 4 + e;
          *(bf16_a*)(Vsh + ((d * 64 + vk * 2) ^ (((d >> 2) & 3) << 4))) =
              (__bf16)v[e];
        }
      }
    }
    __syncthreads();

    // ---- QK^T: S[16 q][32 key] = 2 key-frags x 4 d-chunks of MFMA
    floatx4 sa0 = {0.f, 0.f, 0.f, 0.f};
    floatx4 sa1 = {0.f, 0.f, 0.f, 0.f};
    {
      const int kswz = (l15 & 7) << 4;  // (key&7) == (l15&7) for both frags
#pragma unroll
      for (int c = 0; c < 4; ++c) {
        bf16x8 b0 =
            *(const bf16x8_a*)(Ksh + ((l15 * 256 + c * 64 + g * 16) ^ kswz));
        bf16x8 b1 = *(const bf16x8_a*)(Ksh +
                                       (((l15 + 16) * 256 + c * 64 + g * 16) ^
                                        kswz));
        sa0 = __builtin_amdgcn_mfma_f32_16x16x32_bf16(af[c], b0, sa0, 0, 0, 0);
        sa1 = __builtin_amdgcn_mfma_f32_16x16x32_bf16(af[c], b1, sa1, 0, 0, 0);
      }
    }

    // ---- causal mask + online softmax. D layout: col=l15 (key within
    // frag), row = 4*g + i (q-row). Row's 32 scores live across the 16
    // lanes of this lane-group (2 frags in-lane) -> 4-step shfl_xor reduce.
    float p0a[4], p1a[4];
#pragma unroll
    for (int i = 0; i < 4; ++i) {
      const int qg = q0 + 4 * g + i;
      float s0 = sa0[i];
      float s1 = sa1[i];
      if (kb + l15 > qg) s0 = -3e38f;
      if (kb + 16 + l15 > qg) s1 = -3e38f;
      float t = fmaxf(s0, s1);
      t = fmaxf(t, __shfl_xor(t, 1));
      t = fmaxf(t, __shfl_xor(t, 2));
      t = fmaxf(t, __shfl_xor(t, 4));
      t = fmaxf(t, __shfl_xor(t, 8));
      const float mn = fmaxf(mrow[i], t);
      const float al = __expf(mrow[i] - mn);  // first tile: expf(-inf)=0
      const float e0 = __expf(s0 - mn);       // masked: expf(-huge)=0
      const float e1 = __expf(s1 - mn);
      float ps = e0 + e1;
      ps += __shfl_xor(ps, 1);
      ps += __shfl_xor(ps, 2);
      ps += __shfl_xor(ps, 4);
      ps += __shfl_xor(ps, 8);
      lrow[i] = lrow[i] * al + ps;
      mrow[i] = mn;
      alpha[i] = al;
      p0a[i] = e0;
      p1a[i] = e1;
    }
    // rescale O accumulators (O rows == S rows per-lane)
#pragma unroll
    for (int df = 0; df < 8; ++df)
#pragma unroll
      for (int i = 0; i < 4; ++i) oacc[df][i] *= alpha[i];

    // ---- P -> per-wave LDS (D layout) then re-read as A-frag layout.
#pragma unroll
    for (int i = 0; i < 4; ++i) {
      const int row = 4 * g + i;
      const int sw = ((row >> 1) & 3) << 4;
      *(bf16_a*)(pb + ((row * 64 + l15 * 2) ^ sw)) = (__bf16)p0a[i];
      *(bf16_a*)(pb + ((row * 64 + (16 + l15) * 2) ^ sw)) = (__bf16)p1a[i];
    }
    // same-wave LDS RAW: compiler inserts lgkmcnt wait; no barrier needed.
    bf16x8 pa = *(const bf16x8_a*)(pb + ((l15 * 64 + g * 16) ^
                                         (((l15 >> 1) & 3) << 4)));

    // ---- PV: O[16 q][128 d] += P[16][32] * V[32][128], 8 d-frags, K=32.
    {
      const int vswz = ((l15 >> 2) & 3) << 4;  // ((d>>2)&3) with d=df*16+l15
#pragma unroll
      for (int df = 0; df < 8; ++df) {
        const int d = df * 16 + l15;
        bf16x8 vb = *(const bf16x8_a*)(Vsh + ((d * 64 + g * 16) ^ vswz));
        oacc[df] =
            __builtin_amdgcn_mfma_f32_16x16x32_bf16(pa, vb, oacc[df], 0, 0, 0);
      }
    }
  }

  // ---- epilogue: divide by l, store fp32
  float* ob = out + (size_t)(b * S + q0) * (NH * HD) + h * HD;
#pragma unroll
  for (int i = 0; i < 4; ++i) {
    const float inv = 1.f / lrow[i];
    const int row = 4 * g + i;
#pragma unroll
    for (int df = 0; df < 8; ++df)
      ob[(size_t)row * (NH * HD) + df * 16 + l15] = oacc[df][i] * inv;
  }
}

// ---------------------------------------------------------------------------
extern "C" void kernel_launch(void* const* d_in, const int* in_sizes, int n_in,
                              void* d_out, int out_size, void* d_ws,
                              size_t ws_size, hipStream_t stream) {
  const float* hidden = (const float*)d_in[0];  // (T, DM)
  const float* w_qkv = (const float*)d_in[1];   // (DM, QKVN)
  const float* cosb = (const float*)d_in[2];    // (T, HD)
  const float* sinb = (const float*)d_in[3];    // (T, HD)
  float* out = (float*)d_out;                   // (T, NH*HD) fp32

  char* ws = (char*)d_ws;
  float* qkv = (float*)ws;  // (T, QKVN) fp32, 48 MiB

  gemm_naive<<<dim3(QKVN / 64, T / 64), 256, 0, stream>>>(hidden, w_qkv, qkv);
  rope_kernel<<<(T * (NH + NKVH) * 64) / 256, 256, 0, stream>>>(qkv, cosb,
                                                                sinb);
  // one block per (b, kvh, 16-row q-block): 2*8*64 = 1024 blocks
  attn_mfma<<<dim3(B * NKVH * (S / 16)), 256, 0, stream>>>(qkv, out);
}

// Round 3
// 470.874 us; speedup vs baseline: 9.1993x; 3.6841x over previous
//
#include <hip/hip_runtime.h>
#include <hip/hip_bf16.h>
#include <stdint.h>

// Problem constants (fixed by setup_inputs)
constexpr int NH   = 32;            // query heads
constexpr int NKVH = 8;             // kv heads
constexpr int HD   = 128;           // head dim
constexpr int DM   = 4096;          // model dim (K of the GEMM)
constexpr int B    = 2;
constexpr int S    = 1024;
constexpr int T    = B * S;         // 2048
constexpr int QKVN = (NH + 2 * NKVH) * HD;  // 6144
constexpr int KOFF = NH * HD;               // 4096 (k section)
constexpr int VOFF = (NH + NKVH) * HD;      // 5120 (v section)

typedef float floatx4 __attribute__((ext_vector_type(4)));
typedef floatx4 floatx4_a __attribute__((may_alias));
typedef __bf16 bf16x8 __attribute__((ext_vector_type(8)));
typedef bf16x8 bf16x8_a __attribute__((may_alias));
typedef __bf16 bf16_a __attribute__((may_alias));

__device__ __forceinline__ void gload_lds16(const void* g, void* l) {
  __builtin_amdgcn_global_load_lds(
      (const __attribute__((address_space(1))) void*)g,
      (__attribute__((address_space(3))) void*)l, 16, 0, 0);
}

// ---------------------------------------------------------------------------
// 0a) hidden (T x DM fp32) -> A16 (T x DM bf16). Pure elementwise.
//     NOTE: storage type is raw __bf16 everywhere (NOT __hip_bfloat16 — its
//     operator= has no __bf16 overload on ROCm 7.2; round-2 compile failure).
// ---------------------------------------------------------------------------
__global__ __launch_bounds__(256) void convert_a(const float* __restrict__ A,
                                                 __bf16* __restrict__ A16) {
  const size_t i = (size_t)(blockIdx.x * 256 + threadIdx.x) * 8;
  floatx4 v0 = *(const floatx4_a*)(A + i);
  floatx4 v1 = *(const floatx4_a*)(A + i + 4);
  bf16x8 o;
#pragma unroll
  for (int e = 0; e < 4; ++e) {
    o[e] = (__bf16)v0[e];
    o[e + 4] = (__bf16)v1[e];
  }
  *(bf16x8_a*)(A16 + i) = o;
}

// ---------------------------------------------------------------------------
// 0b) w_qkv (DM x QKVN fp32) -> W16T (QKVN x DM bf16), transposed so the
//     GEMM's B operand is K-contiguous (m97 "B^T input" requirement).
//     64x64 tiles through padded LDS; both global sides coalesced.
// ---------------------------------------------------------------------------
__global__ __launch_bounds__(256) void transpose_w(
    const float* __restrict__ W, __bf16* __restrict__ WT) {
  __shared__ __align__(16) __bf16 ls[64][72];  // [n][k], 144B rows (16B mult)
  const int k0 = blockIdx.x * 64;  // DM/64 = 64
  const int n0 = blockIdx.y * 64;  // QKVN/64 = 96
  const int tx = threadIdx.x & 15, ty = threadIdx.x >> 4;
#pragma unroll
  for (int rr = 0; rr < 4; ++rr) {
    const int k = ty + rr * 16;
    floatx4 v = *(const floatx4_a*)(W + (size_t)(k0 + k) * QKVN + n0 + tx * 4);
#pragma unroll
    for (int e = 0; e < 4; ++e) ls[tx * 4 + e][k] = (__bf16)v[e];
  }
  __syncthreads();
#pragma unroll
  for (int it = 0; it < 2; ++it) {
    const int n = (threadIdx.x >> 3) + it * 32;
    const int c = threadIdx.x & 7;
    bf16x8 o = *(const bf16x8_a*)(&ls[n][c * 8]);
    *(bf16x8_a*)(WT + (size_t)(n0 + n) * DM + k0 + c * 8) = o;
  }
}

// ---------------------------------------------------------------------------
// 1) GEMM: C(T x QKVN, fp32) = A16(T x DM) * W16T(QKVN x DM)^T, bf16 MFMA.
//    m97 structure: 128x128 tile, BK=64, 256 thr / 4 waves (2x2), each wave
//    64x64 = 4x4 frags of 16x16x32. global_load_lds width=16 direct staging,
//    LDS linear [128 rows][64 k] bf16; XOR swizzle (chunk ^= row&7) applied
//    on the GLOBAL source during staging and on the ds_read side (rule #21),
//    making frag ds_read_b128 <=2-way (free) instead of 8-way.
// ---------------------------------------------------------------------------
__global__ __launch_bounds__(256) void gemm_mfma(
    const __bf16* __restrict__ A16, const __bf16* __restrict__ W16T,
    float* __restrict__ C) {
  __shared__ __align__(16) __bf16 Asig[128 * 64];  // 16 KB
  __shared__ __align__(16) __bf16 Bsig[128 * 64];  // 16 KB

  const int tid = threadIdx.x;
  const int lane = tid & 63, w = tid >> 6;
  const int l15 = lane & 15, g = lane >> 4;
  const int r7 = l15 & 7;
  const int m0 = blockIdx.x * 128;  // M/128 = 16 (x fastest: shares W panel)
  const int n0 = blockIdx.y * 128;  // N/128 = 48
  const int wrbase = (w >> 1) * 64, wcbase = (w & 1) * 64;

  // staging map: thread t covers row srow (0..31) + 32*j, swizzled k-chunk
  const int srow = tid >> 3;
  const int sce = ((tid & 7) ^ (srow & 7)) << 3;  // element offset (16B unit)
  const __bf16* agp = A16 + (size_t)(m0 + srow) * DM + sce;
  const __bf16* bgp = W16T + (size_t)(n0 + srow) * DM + sce;
  char* al = (char*)Asig + w * 1024;  // wave-uniform LDS bases
  char* bl = (char*)Bsig + w * 1024;

  const char* Abase = (const char*)Asig + (wrbase + l15) * 128;
  const char* Bbase = (const char*)Bsig + (wcbase + l15) * 128;

  floatx4 acc[4][4];
#pragma unroll
  for (int i = 0; i < 4; ++i)
#pragma unroll
    for (int j = 0; j < 4; ++j) acc[i][j] = (floatx4){0.f, 0.f, 0.f, 0.f};

  for (int kk = 0; kk < DM; kk += 64) {
    __syncthreads();  // previous K-step's LDS reads complete
#pragma unroll
    for (int j = 0; j < 4; ++j) {
      gload_lds16(agp + kk + (size_t)(32 * j) * DM, al + j * 4096);
      gload_lds16(bgp + kk + (size_t)(32 * j) * DM, bl + j * 4096);
    }
    __syncthreads();  // compiler drains vmcnt before s_barrier -> tile ready

#pragma unroll
    for (int kh = 0; kh < 2; ++kh) {
      const int sw = (((kh << 2) | g) ^ r7) << 4;  // swizzled 16B chunk
      bf16x8 af[4], bf[4];
#pragma unroll
      for (int i = 0; i < 4; ++i) {
        af[i] = *(const bf16x8_a*)(Abase + i * 2048 + sw);
        bf[i] = *(const bf16x8_a*)(Bbase + i * 2048 + sw);
      }
#pragma unroll
      for (int i = 0; i < 4; ++i)
#pragma unroll
        for (int j = 0; j < 4; ++j)
          acc[i][j] = __builtin_amdgcn_mfma_f32_16x16x32_bf16(af[i], bf[j],
                                                              acc[i][j], 0, 0, 0);
    }
  }

  // epilogue: C/D layout col=l15, row=g*4+ri (field-verified by attn kernel)
#pragma unroll
  for (int i = 0; i < 4; ++i)
#pragma unroll
    for (int j = 0; j < 4; ++j)
#pragma unroll
      for (int ri = 0; ri < 4; ++ri)
        C[(size_t)(m0 + wrbase + i * 16 + g * 4 + ri) * QKVN + n0 + wcbase +
          j * 16 + l15] = acc[i][j][ri];
}

// ---------------------------------------------------------------------------
// 1-fallback) fp32 vector GEMM (round-1 known-good) — used only if the
// workspace is too small for the bf16 staging buffers.
// ---------------------------------------------------------------------------
__global__ __launch_bounds__(256) void gemm_naive(
    const float* __restrict__ A, const float* __restrict__ W,
    float* __restrict__ C) {
  __shared__ float As[16][65];
  __shared__ float Bs[16][64];
  const int tid = threadIdx.x;
  const int tx = tid & 15, ty = tid >> 4;
  const int m0 = blockIdx.y * 64, n0 = blockIdx.x * 64;
  const int sm = tid >> 2, sk4 = (tid & 3) * 4;
  const int bk = tid >> 4, bn4 = (tid & 15) * 4;
  float acc[4][4];
#pragma unroll
  for (int i = 0; i < 4; ++i)
#pragma unroll
    for (int j = 0; j < 4; ++j) acc[i][j] = 0.f;
  for (int kk = 0; kk < DM; kk += 16) {
    __syncthreads();
    floatx4 va = *(const floatx4_a*)(A + (size_t)(m0 + sm) * DM + kk + sk4);
#pragma unroll
    for (int e = 0; e < 4; ++e) As[sk4 + e][sm] = va[e];
    floatx4 vb = *(const floatx4_a*)(W + (size_t)(kk + bk) * QKVN + n0 + bn4);
    *(floatx4*)&Bs[bk][bn4] = vb;
    __syncthreads();
#pragma unroll
    for (int k = 0; k < 16; ++k) {
      float a[4], b[4];
#pragma unroll
      for (int e = 0; e < 4; ++e) a[e] = As[k][ty * 4 + e];
#pragma unroll
      for (int e = 0; e < 4; ++e) b[e] = Bs[k][tx * 4 + e];
#pragma unroll
      for (int i = 0; i < 4; ++i)
#pragma unroll
        for (int j = 0; j < 4; ++j) acc[i][j] += a[i] * b[j];
    }
  }
#pragma unroll
  for (int i = 0; i < 4; ++i)
#pragma unroll
    for (int j = 0; j < 4; ++j)
      C[(size_t)(m0 + ty * 4 + i) * QKVN + n0 + tx * 4 + j] = acc[i][j];
}

// ---------------------------------------------------------------------------
// 2) RoPE in-place on q and k sections of qkv (fp32). Unchanged.
// ---------------------------------------------------------------------------
__global__ __launch_bounds__(256) void rope_kernel(
    float* __restrict__ qkv, const float* __restrict__ cs,
    const float* __restrict__ sn) {
  const int idx = blockIdx.x * 256 + threadIdx.x;
  const int d = idx & 63;
  const int tmp = idx >> 6;
  const int head = tmp % (NH + NKVH);
  const int tt = tmp / (NH + NKVH);
  float* row = qkv + (size_t)tt * QKVN + head * HD;
  const float c = cs[tt * HD + d];
  const float s = sn[tt * HD + d];
  const float x1 = row[d];
  const float x2 = row[d + 64];
  row[d] = x1 * c - x2 * s;
  row[d + 64] = x2 * c + x1 * s;
}

// ---------------------------------------------------------------------------
// 3) Flash attention, bf16 MFMA (16x16x32), fp32 softmax/accum. Unchanged
//    from round 1 (passed, ~170 us).
// ---------------------------------------------------------------------------
__global__ __launch_bounds__(256) void attn_mfma(
    const float* __restrict__ qkv, float* __restrict__ out) {
  __shared__ __align__(16) char Ksh[32 * 128 * 2];
  __shared__ __align__(16) char Vsh[128 * 32 * 2];
  __shared__ __align__(16) char Psh[4][16 * 32 * 2];

  const int tid = threadIdx.x;
  const int lane = tid & 63, wave = tid >> 6;
  const int bid = (int)blockIdx.x;
  const int qb = bid & 63;
  const int kvh = (bid >> 6) & 7;
  const int b = bid >> 9;
  const int q0 = qb * 16;
  const int h = kvh * 4 + wave;
  const int NT = (q0 + 47) >> 5;
  const float scale = 0.08838834764831845f;

  const int l15 = lane & 15, g = lane >> 4;

  bf16x8 af[4];
  {
    const float* qr = qkv + (size_t)(b * S + q0 + l15) * QKVN + h * HD;
#pragma unroll
    for (int c = 0; c < 4; ++c) {
      const int d0 = c * 32 + g * 8;
      floatx4 f0 = *(const floatx4_a*)(qr + d0);
      floatx4 f1 = *(const floatx4_a*)(qr + d0 + 4);
      bf16x8 a;
#pragma unroll
      for (int e = 0; e < 4; ++e) {
        a[e] = (__bf16)(f0[e] * scale);
        a[e + 4] = (__bf16)(f1[e] * scale);
      }
      af[c] = a;
    }
  }

  floatx4 oacc[8];
#pragma unroll
  for (int i = 0; i < 8; ++i) oacc[i] = (floatx4){0.f, 0.f, 0.f, 0.f};
  float mrow[4], lrow[4], alpha[4];
#pragma unroll
  for (int i = 0; i < 4; ++i) {
    mrow[i] = -__builtin_inff();
    lrow[i] = 0.f;
  }

  const int krow = tid >> 3, kdb = (tid & 7) * 16;
  const int vk = tid & 31, vdb = (tid >> 5) * 16;
  const float* kbaseg = qkv + (size_t)(b * S) * QKVN + KOFF + kvh * HD;
  const float* vbaseg = qkv + (size_t)(b * S) * QKVN + VOFF + kvh * HD;
  char* pb = (char*)Psh[wave];

  for (int kt = 0; kt < NT; ++kt) {
    const int kb = kt * 32;
    __syncthreads();
    {
      const float* src = kbaseg + (size_t)(kb + krow) * QKVN + kdb;
      floatx4 v0 = *(const floatx4_a*)(src);
      floatx4 v1 = *(const floatx4_a*)(src + 4);
      floatx4 v2 = *(const floatx4_a*)(src + 8);
      floatx4 v3 = *(const floatx4_a*)(src + 12);
      bf16x8 p0, p1;
#pragma unroll
      for (int e = 0; e < 4; ++e) {
        p0[e] = (__bf16)v0[e];
        p0[e + 4] = (__bf16)v1[e];
        p1[e] = (__bf16)v2[e];
        p1[e + 4] = (__bf16)v3[e];
      }
      const int swz = (krow & 7) << 4;
      const int base = krow * 256 + kdb * 2;
      *(bf16x8_a*)(Ksh + ((base) ^ swz)) = p0;
      *(bf16x8_a*)(Ksh + ((base + 16) ^ swz)) = p1;
    }
    {
      const float* src = vbaseg + (size_t)(kb + vk) * QKVN + vdb;
#pragma unroll
      for (int q4 = 0; q4 < 4; ++q4) {
        floatx4 v = *(const floatx4_a*)(src + q4 * 4);
#pragma unroll
        for (int e = 0; e < 4; ++e) {
          const int d = vdb + q4 * 4 + e;
          *(bf16_a*)(Vsh + ((d * 64 + vk * 2) ^ (((d >> 2) & 3) << 4))) =
              (__bf16)v[e];
        }
      }
    }
    __syncthreads();

    floatx4 sa0 = {0.f, 0.f, 0.f, 0.f};
    floatx4 sa1 = {0.f, 0.f, 0.f, 0.f};
    {
      const int kswz = (l15 & 7) << 4;
#pragma unroll
      for (int c = 0; c < 4; ++c) {
        bf16x8 b0 =
            *(const bf16x8_a*)(Ksh + ((l15 * 256 + c * 64 + g * 16) ^ kswz));
        bf16x8 b1 = *(const bf16x8_a*)(Ksh +
                                       (((l15 + 16) * 256 + c * 64 + g * 16) ^
                                        kswz));
        sa0 = __builtin_amdgcn_mfma_f32_16x16x32_bf16(af[c], b0, sa0, 0, 0, 0);
        sa1 = __builtin_amdgcn_mfma_f32_16x16x32_bf16(af[c], b1, sa1, 0, 0, 0);
      }
    }

    float p0a[4], p1a[4];
#pragma unroll
    for (int i = 0; i < 4; ++i) {
      const int qg = q0 + 4 * g + i;
      float s0 = sa0[i];
      float s1 = sa1[i];
      if (kb + l15 > qg) s0 = -3e38f;
      if (kb + 16 + l15 > qg) s1 = -3e38f;
      float t = fmaxf(s0, s1);
      t = fmaxf(t, __shfl_xor(t, 1));
      t = fmaxf(t, __shfl_xor(t, 2));
      t = fmaxf(t, __shfl_xor(t, 4));
      t = fmaxf(t, __shfl_xor(t, 8));
      const float mn = fmaxf(mrow[i], t);
      const float al = __expf(mrow[i] - mn);
      const float e0 = __expf(s0 - mn);
      const float e1 = __expf(s1 - mn);
      float ps = e0 + e1;
      ps += __shfl_xor(ps, 1);
      ps += __shfl_xor(ps, 2);
      ps += __shfl_xor(ps, 4);
      ps += __shfl_xor(ps, 8);
      lrow[i] = lrow[i] * al + ps;
      mrow[i] = mn;
      alpha[i] = al;
      p0a[i] = e0;
      p1a[i] = e1;
    }
#pragma unroll
    for (int df = 0; df < 8; ++df)
#pragma unroll
      for (int i = 0; i < 4; ++i) oacc[df][i] *= alpha[i];

#pragma unroll
    for (int i = 0; i < 4; ++i) {
      const int row = 4 * g + i;
      const int sw = ((row >> 1) & 3) << 4;
      *(bf16_a*)(pb + ((row * 64 + l15 * 2) ^ sw)) = (__bf16)p0a[i];
      *(bf16_a*)(pb + ((row * 64 + (16 + l15) * 2) ^ sw)) = (__bf16)p1a[i];
    }
    bf16x8 pa = *(const bf16x8_a*)(pb + ((l15 * 64 + g * 16) ^
                                         (((l15 >> 1) & 3) << 4)));

    {
      const int vswz = ((l15 >> 2) & 3) << 4;
#pragma unroll
      for (int df = 0; df < 8; ++df) {
        const int d = df * 16 + l15;
        bf16x8 vb = *(const bf16x8_a*)(Vsh + ((d * 64 + g * 16) ^ vswz));
        oacc[df] =
            __builtin_amdgcn_mfma_f32_16x16x32_bf16(pa, vb, oacc[df], 0, 0, 0);
      }
    }
  }

  float* ob = out + (size_t)(b * S + q0) * (NH * HD) + h * HD;
#pragma unroll
  for (int i = 0; i < 4; ++i) {
    const float inv = 1.f / lrow[i];
    const int row = 4 * g + i;
#pragma unroll
    for (int df = 0; df < 8; ++df)
      ob[(size_t)row * (NH * HD) + df * 16 + l15] = oacc[df][i] * inv;
  }
}

// ---------------------------------------------------------------------------
extern "C" void kernel_launch(void* const* d_in, const int* in_sizes, int n_in,
                              void* d_out, int out_size, void* d_ws,
                              size_t ws_size, hipStream_t stream) {
  const float* hidden = (const float*)d_in[0];  // (T, DM)
  const float* w_qkv = (const float*)d_in[1];   // (DM, QKVN)
  const float* cosb = (const float*)d_in[2];    // (T, HD)
  const float* sinb = (const float*)d_in[3];    // (T, HD)
  float* out = (float*)d_out;                   // (T, NH*HD) fp32

  char* ws = (char*)d_ws;
  float* qkv = (float*)ws;                        // (T, QKVN) fp32, 50.3 MB
  const size_t qkv_bytes = (size_t)T * QKVN * 4;
  const size_t wt_bytes = (size_t)QKVN * DM * 2;  // 50.3 MB
  const size_t a16_bytes = (size_t)T * DM * 2;    // 16.8 MB

  if (ws_size >= qkv_bytes + wt_bytes + a16_bytes) {
    __bf16* W16T = (__bf16*)(ws + qkv_bytes);
    __bf16* A16 = (__bf16*)(ws + qkv_bytes + wt_bytes);
    convert_a<<<(T * DM) / (256 * 8), 256, 0, stream>>>(hidden, A16);
    transpose_w<<<dim3(DM / 64, QKVN / 64), 256, 0, stream>>>(w_qkv, W16T);
    gemm_mfma<<<dim3(T / 128, QKVN / 128), 256, 0, stream>>>(A16, W16T, qkv);
  } else {
    gemm_naive<<<dim3(QKVN / 64, T / 64), 256, 0, stream>>>(hidden, w_qkv,
                                                            qkv);
  }
  rope_kernel<<<(T * (NH + NKVH) * 64) / 256, 256, 0, stream>>>(qkv, cosb,
                                                                sinb);
  attn_mfma<<<dim3(B * NKVH * (S / 16)), 256, 0, stream>>>(qkv, out);
}

// Round 6
// 435.149 us; speedup vs baseline: 9.9546x; 1.0821x over previous
//
#include <hip/hip_runtime.h>
#include <hip/hip_bf16.h>
#include <stdint.h>

// Problem constants (fixed by setup_inputs)
constexpr int NH   = 32;            // query heads
constexpr int NKVH = 8;             // kv heads
constexpr int HD   = 128;           // head dim
constexpr int DM   = 4096;          // model dim (K of the GEMM)
constexpr int B    = 2;
constexpr int S    = 1024;
constexpr int T    = B * S;         // 2048
constexpr int QKVN = (NH + 2 * NKVH) * HD;  // 6144
constexpr int KOFF = NH * HD;               // 4096 (k section)
constexpr int VOFF = (NH + NKVH) * HD;      // 5120 (v section)

typedef float floatx4 __attribute__((ext_vector_type(4)));
typedef floatx4 floatx4_a __attribute__((may_alias));
typedef __bf16 bf16x8 __attribute__((ext_vector_type(8)));
typedef bf16x8 bf16x8_a __attribute__((may_alias));
typedef __bf16 bf16_a __attribute__((may_alias));

__device__ __forceinline__ void gload_lds16(const void* g, void* l) {
  __builtin_amdgcn_global_load_lds(
      (const __attribute__((address_space(1))) void*)g,
      (__attribute__((address_space(3))) void*)l, 16, 0, 0);
}

// ---------------------------------------------------------------------------
// 0a) hidden (T x DM fp32) -> A16 (T x DM bf16). Pure elementwise.
//     Storage type raw __bf16 (NOT __hip_bfloat16: no __bf16 operator= on
//     ROCm 7.2 — round-2 compile failure).
// ---------------------------------------------------------------------------
__global__ __launch_bounds__(256) void convert_a(const float* __restrict__ A,
                                                 __bf16* __restrict__ A16) {
  const size_t i = (size_t)(blockIdx.x * 256 + threadIdx.x) * 8;
  floatx4 v0 = *(const floatx4_a*)(A + i);
  floatx4 v1 = *(const floatx4_a*)(A + i + 4);
  bf16x8 o;
#pragma unroll
  for (int e = 0; e < 4; ++e) {
    o[e] = (__bf16)v0[e];
    o[e + 4] = (__bf16)v1[e];
  }
  *(bf16x8_a*)(A16 + i) = o;
}

// ---------------------------------------------------------------------------
// 0b) w_qkv (DM x QKVN fp32) -> W16T (QKVN x DM bf16), transposed so the
//     GEMM's B operand is K-contiguous. 64x64 tiles through padded LDS.
// ---------------------------------------------------------------------------
__global__ __launch_bounds__(256) void transpose_w(
    const float* __restrict__ W, __bf16* __restrict__ WT) {
  __shared__ __align__(16) __bf16 ls[64][72];  // [n][k], 144B rows (16B mult)
  const int k0 = blockIdx.x * 64;  // DM/64 = 64
  const int n0 = blockIdx.y * 64;  // QKVN/64 = 96
  const int tx = threadIdx.x & 15, ty = threadIdx.x >> 4;
#pragma unroll
  for (int rr = 0; rr < 4; ++rr) {
    const int k = ty + rr * 16;
    floatx4 v = *(const floatx4_a*)(W + (size_t)(k0 + k) * QKVN + n0 + tx * 4);
#pragma unroll
    for (int e = 0; e < 4; ++e) ls[tx * 4 + e][k] = (__bf16)v[e];
  }
  __syncthreads();
#pragma unroll
  for (int it = 0; it < 2; ++it) {
    const int n = (threadIdx.x >> 3) + it * 32;
    const int c = threadIdx.x & 7;
    bf16x8 o = *(const bf16x8_a*)(&ls[n][c * 8]);
    *(bf16x8_a*)(WT + (size_t)(n0 + n) * DM + k0 + c * 8) = o;
  }
}

// ---------------------------------------------------------------------------
// 1) GEMM: C(T x QKVN, fp32) = A16(T x DM) * W16T(QKVN x DM)^T, bf16 MFMA.
//    m97 structure: 128x128 tile, BK=64, 4 waves (2x2), wave 64x64 = 4x4
//    frags of 16x16x32. global_load_lds width=16 direct staging; XOR swizzle
//    on GLOBAL source + ds_read side (rule #21). Unchanged from round 3
//    (measured <170 us).
// ---------------------------------------------------------------------------
__global__ __launch_bounds__(256) void gemm_mfma(
    const __bf16* __restrict__ A16, const __bf16* __restrict__ W16T,
    float* __restrict__ C) {
  __shared__ __align__(16) __bf16 Asig[128 * 64];  // 16 KB
  __shared__ __align__(16) __bf16 Bsig[128 * 64];  // 16 KB

  const int tid = threadIdx.x;
  const int lane = tid & 63, w = tid >> 6;
  const int l15 = lane & 15, g = lane >> 4;
  const int r7 = l15 & 7;
  const int m0 = blockIdx.x * 128;
  const int n0 = blockIdx.y * 128;
  const int wrbase = (w >> 1) * 64, wcbase = (w & 1) * 64;

  const int srow = tid >> 3;
  const int sce = ((tid & 7) ^ (srow & 7)) << 3;
  const __bf16* agp = A16 + (size_t)(m0 + srow) * DM + sce;
  const __bf16* bgp = W16T + (size_t)(n0 + srow) * DM + sce;
  char* al = (char*)Asig + w * 1024;
  char* bl = (char*)Bsig + w * 1024;

  const char* Abase = (const char*)Asig + (wrbase + l15) * 128;
  const char* Bbase = (const char*)Bsig + (wcbase + l15) * 128;

  floatx4 acc[4][4];
#pragma unroll
  for (int i = 0; i < 4; ++i)
#pragma unroll
    for (int j = 0; j < 4; ++j) acc[i][j] = (floatx4){0.f, 0.f, 0.f, 0.f};

  for (int kk = 0; kk < DM; kk += 64) {
    __syncthreads();
#pragma unroll
    for (int j = 0; j < 4; ++j) {
      gload_lds16(agp + kk + (size_t)(32 * j) * DM, al + j * 4096);
      gload_lds16(bgp + kk + (size_t)(32 * j) * DM, bl + j * 4096);
    }
    __syncthreads();

#pragma unroll
    for (int kh = 0; kh < 2; ++kh) {
      const int sw = (((kh << 2) | g) ^ r7) << 4;
      bf16x8 af[4], bf[4];
#pragma unroll
      for (int i = 0; i < 4; ++i) {
        af[i] = *(const bf16x8_a*)(Abase + i * 2048 + sw);
        bf[i] = *(const bf16x8_a*)(Bbase + i * 2048 + sw);
      }
#pragma unroll
      for (int i = 0; i < 4; ++i)
#pragma unroll
        for (int j = 0; j < 4; ++j)
          acc[i][j] = __builtin_amdgcn_mfma_f32_16x16x32_bf16(af[i], bf[j],
                                                              acc[i][j], 0, 0, 0);
    }
  }

#pragma unroll
  for (int i = 0; i < 4; ++i)
#pragma unroll
    for (int j = 0; j < 4; ++j)
#pragma unroll
      for (int ri = 0; ri < 4; ++ri)
        C[(size_t)(m0 + wrbase + i * 16 + g * 4 + ri) * QKVN + n0 + wcbase +
          j * 16 + l15] = acc[i][j][ri];
}

// ---------------------------------------------------------------------------
// 1-fallback) fp32 vector GEMM (round-1 known-good) — used only if the
// workspace is too small for the bf16 staging buffers.
// ---------------------------------------------------------------------------
__global__ __launch_bounds__(256) void gemm_naive(
    const float* __restrict__ A, const float* __restrict__ W,
    float* __restrict__ C) {
  __shared__ float As[16][65];
  __shared__ float Bs[16][64];
  const int tid = threadIdx.x;
  const int tx = tid & 15, ty = tid >> 4;
  const int m0 = blockIdx.y * 64, n0 = blockIdx.x * 64;
  const int sm = tid >> 2, sk4 = (tid & 3) * 4;
  const int bk = tid >> 4, bn4 = (tid & 15) * 4;
  float acc[4][4];
#pragma unroll
  for (int i = 0; i < 4; ++i)
#pragma unroll
    for (int j = 0; j < 4; ++j) acc[i][j] = 0.f;
  for (int kk = 0; kk < DM; kk += 16) {
    __syncthreads();
    floatx4 va = *(const floatx4_a*)(A + (size_t)(m0 + sm) * DM + kk + sk4);
#pragma unroll
    for (int e = 0; e < 4; ++e) As[sk4 + e][sm] = va[e];
    floatx4 vb = *(const floatx4_a*)(W + (size_t)(kk + bk) * QKVN + n0 + bn4);
    *(floatx4*)&Bs[bk][bn4] = vb;
    __syncthreads();
#pragma unroll
    for (int k = 0; k < 16; ++k) {
      float a[4], b[4];
#pragma unroll
      for (int e = 0; e < 4; ++e) a[e] = As[k][ty * 4 + e];
#pragma unroll
      for (int e = 0; e < 4; ++e) b[e] = Bs[k][tx * 4 + e];
#pragma unroll
      for (int i = 0; i < 4; ++i)
#pragma unroll
        for (int j = 0; j < 4; ++j) acc[i][j] += a[i] * b[j];
    }
  }
#pragma unroll
  for (int i = 0; i < 4; ++i)
#pragma unroll
    for (int j = 0; j < 4; ++j)
      C[(size_t)(m0 + ty * 4 + i) * QKVN + n0 + tx * 4 + j] = acc[i][j];
}

// ---------------------------------------------------------------------------
// 2) Flash attention, bf16 MFMA, fp32 softmax/accum. Round-4 changes:
//    (a) causal WORK-BALANCE remap: co-scheduled blocks (bid +256k) get
//        complementary qb -> NT(qb)+NT(63-qb) ~ const (was: same qb, 2x
//        max/mean imbalance; measured Occupancy 11.8%).
//    (b) RoPE fused in-kernel (rope_kernel pass deleted): Q-rope at fragment
//        load (pair d<->d+64 is af[c]<->af[c+2], in-lane); K-rope in staging
//        regs before bf16 cvt (thread holds both halves of the pair: d in
//        [8t,8t+8) and +64). fp32 math identical to the old rope pass.
// ---------------------------------------------------------------------------
__global__ __launch_bounds__(256) void attn_mfma(
    const float* __restrict__ qkv, const float* __restrict__ cosp,
    const float* __restrict__ sinp, float* __restrict__ out) {
  __shared__ __align__(16) char Ksh[32 * 128 * 2];
  __shared__ __align__(16) char Vsh[128 * 32 * 2];
  __shared__ __align__(16) char Psh[4][16 * 32 * 2];

  const int tid = threadIdx.x;
  const int lane = tid & 63, wave = tid >> 6;
  const int raw = (int)blockIdx.x;
  const int qb_raw = raw & 63;
  const int qb = ((raw >> 8) & 1) ? (63 - qb_raw) : qb_raw;  // balance remap
  const int kvh = (raw >> 6) & 7;
  const int b = raw >> 9;
  const int q0 = qb * 16;
  const int h = kvh * 4 + wave;
  const int NT = (q0 + 47) >> 5;
  const float scale = 0.08838834764831845f;

  const int l15 = lane & 15, g = lane >> 4;

  // --- Q A-fragments with fused RoPE, pre-scaled. af[c] holds d =
  // c*32+g*8+e; rope pair (d, d+64) = (af[c], af[c+2]) for c<2, same e.
  bf16x8 af[4];
  {
    const size_t tok = (size_t)(b * S + q0 + l15);
    const float* qr = qkv + tok * QKVN + h * HD;
    const float* cr = cosp + tok * HD;
    const float* sr = sinp + tok * HD;
#pragma unroll
    for (int c = 0; c < 2; ++c) {
      const int d0 = c * 32 + g * 8;
      floatx4 x10 = *(const floatx4_a*)(qr + d0);
      floatx4 x11 = *(const floatx4_a*)(qr + d0 + 4);
      floatx4 x20 = *(const floatx4_a*)(qr + d0 + 64);
      floatx4 x21 = *(const floatx4_a*)(qr + d0 + 68);
      floatx4 c0 = *(const floatx4_a*)(cr + d0);
      floatx4 c1 = *(const floatx4_a*)(cr + d0 + 4);
      floatx4 s0 = *(const floatx4_a*)(sr + d0);
      floatx4 s1 = *(const floatx4_a*)(sr + d0 + 4);
      bf16x8 alo, ahi;
#pragma unroll
      for (int e = 0; e < 4; ++e) {
        alo[e] = (__bf16)((x10[e] * c0[e] - x20[e] * s0[e]) * scale);
        alo[e + 4] = (__bf16)((x11[e] * c1[e] - x21[e] * s1[e]) * scale);
        ahi[e] = (__bf16)((x20[e] * c0[e] + x10[e] * s0[e]) * scale);
        ahi[e + 4] = (__bf16)((x21[e] * c1[e] + x11[e] * s1[e]) * scale);
      }
      af[c] = alo;
      af[c + 2] = ahi;
    }
  }

  floatx4 oacc[8];
#pragma unroll
  for (int i = 0; i < 8; ++i) oacc[i] = (floatx4){0.f, 0.f, 0.f, 0.f};
  float mrow[4], lrow[4], alpha[4];
#pragma unroll
  for (int i = 0; i < 4; ++i) {
    mrow[i] = -__builtin_inff();
    lrow[i] = 0.f;
  }

  // K staging: thread covers row krow, d in [kd8, kd8+8) and [kd8+64, +72).
  const int krow = tid >> 3, kd8 = (tid & 7) * 8;
  const int vk = tid & 31, vdb = (tid >> 5) * 16;
  const float* kbaseg = qkv + (size_t)b * S * QKVN + KOFF + kvh * HD;
  const float* vbaseg = qkv + (size_t)b * S * QKVN + VOFF + kvh * HD;
  char* pb = (char*)Psh[wave];

  for (int kt = 0; kt < NT; ++kt) {
    const int kb = kt * 32;
    __syncthreads();
    // ---- stage K tile with fused RoPE: fp32 -> rope -> bf16, swizzled
    {
      const int t = kb + krow;
      const float* src = kbaseg + (size_t)t * QKVN + kd8;
      const float* crk = cosp + (size_t)(b * S + t) * HD + kd8;
      const float* srk = sinp + (size_t)(b * S + t) * HD + kd8;
      floatx4 x10 = *(const floatx4_a*)(src);
      floatx4 x11 = *(const floatx4_a*)(src + 4);
      floatx4 x20 = *(const floatx4_a*)(src + 64);
      floatx4 x21 = *(const floatx4_a*)(src + 68);
      floatx4 c0 = *(const floatx4_a*)(crk);
      floatx4 c1 = *(const floatx4_a*)(crk + 4);
      floatx4 s0 = *(const floatx4_a*)(srk);
      floatx4 s1 = *(const floatx4_a*)(srk + 4);
      bf16x8 plo, phi;
#pragma unroll
      for (int e = 0; e < 4; ++e) {
        plo[e] = (__bf16)(x10[e] * c0[e] - x20[e] * s0[e]);
        plo[e + 4] = (__bf16)(x11[e] * c1[e] - x21[e] * s1[e]);
        phi[e] = (__bf16)(x20[e] * c0[e] + x10[e] * s0[e]);
        phi[e + 4] = (__bf16)(x21[e] * c1[e] + x11[e] * s1[e]);
      }
      const int swz = (krow & 7) << 4;
      const int base = krow * 256 + kd8 * 2;
      *(bf16x8_a*)(Ksh + (base ^ swz)) = plo;
      *(bf16x8_a*)(Ksh + ((base + 128) ^ swz)) = phi;
    }
    // ---- stage V tile transposed: V^T[d][key] bf16, swizzled (no rope)
    {
      const float* src = vbaseg + (size_t)(kb + vk) * QKVN + vdb;
#pragma unroll
      for (int q4 = 0; q4 < 4; ++q4) {
        floatx4 v = *(const floatx4_a*)(src + q4 * 4);
#pragma unroll
        for (int e = 0; e < 4; ++e) {
          const int d = vdb + q4 * 4 + e;
          *(bf16_a*)(Vsh + ((d * 64 + vk * 2) ^ (((d >> 2) & 3) << 4))) =
              (__bf16)v[e];
        }
      }
    }
    __syncthreads();

    // ---- QK^T
    floatx4 sa0 = {0.f, 0.f, 0.f, 0.f};
    floatx4 sa1 = {0.f, 0.f, 0.f, 0.f};
    {
      const int kswz = (l15 & 7) << 4;
#pragma unroll
      for (int c = 0; c < 4; ++c) {
        bf16x8 b0 =
            *(const bf16x8_a*)(Ksh + ((l15 * 256 + c * 64 + g * 16) ^ kswz));
        bf16x8 b1 = *(const bf16x8_a*)(Ksh +
                                       (((l15 + 16) * 256 + c * 64 + g * 16) ^
                                        kswz));
        sa0 = __builtin_amdgcn_mfma_f32_16x16x32_bf16(af[c], b0, sa0, 0, 0, 0);
        sa1 = __builtin_amdgcn_mfma_f32_16x16x32_bf16(af[c], b1, sa1, 0, 0, 0);
      }
    }

    // ---- causal mask + online softmax (rows live in 16-lane groups)
    float p0a[4], p1a[4];
#pragma unroll
    for (int i = 0; i < 4; ++i) {
      const int qg = q0 + 4 * g + i;
      float s0 = sa0[i];
      float s1 = sa1[i];
      if (kb + l15 > qg) s0 = -3e38f;
      if (kb + 16 + l15 > qg) s1 = -3e38f;
      float t = fmaxf(s0, s1);
      t = fmaxf(t, __shfl_xor(t, 1));
      t = fmaxf(t, __shfl_xor(t, 2));
      t = fmaxf(t, __shfl_xor(t, 4));
      t = fmaxf(t, __shfl_xor(t, 8));
      const float mn = fmaxf(mrow[i], t);
      const float al = __expf(mrow[i] - mn);
      const float e0 = __expf(s0 - mn);
      const float e1 = __expf(s1 - mn);
      float ps = e0 + e1;
      ps += __shfl_xor(ps, 1);
      ps += __shfl_xor(ps, 2);
      ps += __shfl_xor(ps, 4);
      ps += __shfl_xor(ps, 8);
      lrow[i] = lrow[i] * al + ps;
      mrow[i] = mn;
      alpha[i] = al;
      p0a[i] = e0;
      p1a[i] = e1;
    }
#pragma unroll
    for (int df = 0; df < 8; ++df)
#pragma unroll
      for (int i = 0; i < 4; ++i) oacc[df][i] *= alpha[i];

    // ---- P -> per-wave LDS (D layout) then re-read as A-frag layout.
#pragma unroll
    for (int i = 0; i < 4; ++i) {
      const int row = 4 * g + i;
      const int sw = ((row >> 1) & 3) << 4;
      *(bf16_a*)(pb + ((row * 64 + l15 * 2) ^ sw)) = (__bf16)p0a[i];
      *(bf16_a*)(pb + ((row * 64 + (16 + l15) * 2) ^ sw)) = (__bf16)p1a[i];
    }
    bf16x8 pa = *(const bf16x8_a*)(pb + ((l15 * 64 + g * 16) ^
                                         (((l15 >> 1) & 3) << 4)));

    // ---- PV
    {
      const int vswz = ((l15 >> 2) & 3) << 4;
#pragma unroll
      for (int df = 0; df < 8; ++df) {
        const int d = df * 16 + l15;
        bf16x8 vb = *(const bf16x8_a*)(Vsh + ((d * 64 + g * 16) ^ vswz));
        oacc[df] =
            __builtin_amdgcn_mfma_f32_16x16x32_bf16(pa, vb, oacc[df], 0, 0, 0);
      }
    }
  }

  float* ob = out + (size_t)(b * S + q0) * (NH * HD) + h * HD;
#pragma unroll
  for (int i = 0; i < 4; ++i) {
    const float inv = 1.f / lrow[i];
    const int row = 4 * g + i;
#pragma unroll
    for (int df = 0; df < 8; ++df)
      ob[(size_t)row * (NH * HD) + df * 16 + l15] = oacc[df][i] * inv;
  }
}

// ---------------------------------------------------------------------------
extern "C" void kernel_launch(void* const* d_in, const int* in_sizes, int n_in,
                              void* d_out, int out_size, void* d_ws,
                              size_t ws_size, hipStream_t stream) {
  const float* hidden = (const float*)d_in[0];  // (T, DM)
  const float* w_qkv = (const float*)d_in[1];   // (DM, QKVN)
  const float* cosb = (const float*)d_in[2];    // (T, HD)
  const float* sinb = (const float*)d_in[3];    // (T, HD)
  float* out = (float*)d_out;                   // (T, NH*HD) fp32

  char* ws = (char*)d_ws;
  float* qkv = (float*)ws;                        // (T, QKVN) fp32, 50.3 MB
  const size_t qkv_bytes = (size_t)T * QKVN * 4;
  const size_t wt_bytes = (size_t)QKVN * DM * 2;  // 50.3 MB
  const size_t a16_bytes = (size_t)T * DM * 2;    // 16.8 MB

  if (ws_size >= qkv_bytes + wt_bytes + a16_bytes) {
    __bf16* W16T = (__bf16*)(ws + qkv_bytes);
    __bf16* A16 = (__bf16*)(ws + qkv_bytes + wt_bytes);
    convert_a<<<(T * DM) / (256 * 8), 256, 0, stream>>>(hidden, A16);
    transpose_w<<<dim3(DM / 64, QKVN / 64), 256, 0, stream>>>(w_qkv, W16T);
    gemm_mfma<<<dim3(T / 128, QKVN / 128), 256, 0, stream>>>(A16, W16T, qkv);
  } else {
    gemm_naive<<<dim3(QKVN / 64, T / 64), 256, 0, stream>>>(hidden, w_qkv,
                                                            qkv);
  }
  // RoPE is fused into attn_mfma (Q at fragment load, K at staging).
  attn_mfma<<<dim3(B * NKVH * (S / 16)), 256, 0, stream>>>(qkv, cosb, sinb,
                                                           out);
}

// Round 8
// 397.457 us; speedup vs baseline: 10.8986x; 1.0948x over previous
//
#include <hip/hip_runtime.h>
#include <hip/hip_bf16.h>
#include <stdint.h>

// Problem constants (fixed by setup_inputs)
constexpr int NH   = 32;            // query heads
constexpr int NKVH = 8;             // kv heads
constexpr int HD   = 128;           // head dim
constexpr int DM   = 4096;          // model dim (K of the GEMM)
constexpr int B    = 2;
constexpr int S    = 1024;
constexpr int T    = B * S;         // 2048
constexpr int QKVN = (NH + 2 * NKVH) * HD;  // 6144
constexpr int KOFF = NH * HD;               // 4096 (k section)
constexpr int VOFF = (NH + NKVH) * HD;      // 5120 (v section)
constexpr int KVB  = 64;                    // attn key-tile (was 32)
constexpr int NKT  = S / KVB;               // 16 tiles per (b,kvh)
constexpr int TILE_B = KVB * HD * 2;        // 16384 bytes per K or V^T tile

typedef float floatx4 __attribute__((ext_vector_type(4)));
typedef floatx4 floatx4_a __attribute__((may_alias));
typedef __bf16 bf16x8 __attribute__((ext_vector_type(8)));
typedef bf16x8 bf16x8_a __attribute__((may_alias));
typedef __bf16 bf16_a __attribute__((may_alias));

__device__ __forceinline__ void gload_lds16(const void* g, void* l) {
  __builtin_amdgcn_global_load_lds(
      (const __attribute__((address_space(1))) void*)g,
      (__attribute__((address_space(3))) void*)l, 16, 0, 0);
}

// ---------------------------------------------------------------------------
// 0a) hidden (T x DM fp32) -> A16 (T x DM bf16).
// ---------------------------------------------------------------------------
__global__ __launch_bounds__(256) void convert_a(const float* __restrict__ A,
                                                 __bf16* __restrict__ A16) {
  const size_t i = (size_t)(blockIdx.x * 256 + threadIdx.x) * 8;
  floatx4 v0 = *(const floatx4_a*)(A + i);
  floatx4 v1 = *(const floatx4_a*)(A + i + 4);
  bf16x8 o;
#pragma unroll
  for (int e = 0; e < 4; ++e) {
    o[e] = (__bf16)v0[e];
    o[e + 4] = (__bf16)v1[e];
  }
  *(bf16x8_a*)(A16 + i) = o;
}

// ---------------------------------------------------------------------------
// 0b) w_qkv (DM x QKVN fp32) -> W16T (QKVN x DM bf16), K-contiguous B^T.
// ---------------------------------------------------------------------------
__global__ __launch_bounds__(256) void transpose_w(
    const float* __restrict__ W, __bf16* __restrict__ WT) {
  __shared__ __align__(16) __bf16 ls[64][72];
  const int k0 = blockIdx.x * 64;
  const int n0 = blockIdx.y * 64;
  const int tx = threadIdx.x & 15, ty = threadIdx.x >> 4;
#pragma unroll
  for (int rr = 0; rr < 4; ++rr) {
    const int k = ty + rr * 16;
    floatx4 v = *(const floatx4_a*)(W + (size_t)(k0 + k) * QKVN + n0 + tx * 4);
#pragma unroll
    for (int e = 0; e < 4; ++e) ls[tx * 4 + e][k] = (__bf16)v[e];
  }
  __syncthreads();
#pragma unroll
  for (int it = 0; it < 2; ++it) {
    const int n = (threadIdx.x >> 3) + it * 32;
    const int c = threadIdx.x & 7;
    bf16x8 o = *(const bf16x8_a*)(&ls[n][c * 8]);
    *(bf16x8_a*)(WT + (size_t)(n0 + n) * DM + k0 + c * 8) = o;
  }
}

// ---------------------------------------------------------------------------
// 1) GEMM (unchanged round-3 structure, measured <170 us).
// ---------------------------------------------------------------------------
__global__ __launch_bounds__(256) void gemm_mfma(
    const __bf16* __restrict__ A16, const __bf16* __restrict__ W16T,
    float* __restrict__ C) {
  __shared__ __align__(16) __bf16 Asig[128 * 64];
  __shared__ __align__(16) __bf16 Bsig[128 * 64];

  const int tid = threadIdx.x;
  const int lane = tid & 63, w = tid >> 6;
  const int l15 = lane & 15, g = lane >> 4;
  const int r7 = l15 & 7;
  const int m0 = blockIdx.x * 128;
  const int n0 = blockIdx.y * 128;
  const int wrbase = (w >> 1) * 64, wcbase = (w & 1) * 64;

  const int srow = tid >> 3;
  const int sce = ((tid & 7) ^ (srow & 7)) << 3;
  const __bf16* agp = A16 + (size_t)(m0 + srow) * DM + sce;
  const __bf16* bgp = W16T + (size_t)(n0 + srow) * DM + sce;
  char* al = (char*)Asig + w * 1024;
  char* bl = (char*)Bsig + w * 1024;

  const char* Abase = (const char*)Asig + (wrbase + l15) * 128;
  const char* Bbase = (const char*)Bsig + (wcbase + l15) * 128;

  floatx4 acc[4][4];
#pragma unroll
  for (int i = 0; i < 4; ++i)
#pragma unroll
    for (int j = 0; j < 4; ++j) acc[i][j] = (floatx4){0.f, 0.f, 0.f, 0.f};

  for (int kk = 0; kk < DM; kk += 64) {
    __syncthreads();
#pragma unroll
    for (int j = 0; j < 4; ++j) {
      gload_lds16(agp + kk + (size_t)(32 * j) * DM, al + j * 4096);
      gload_lds16(bgp + kk + (size_t)(32 * j) * DM, bl + j * 4096);
    }
    __syncthreads();

#pragma unroll
    for (int kh = 0; kh < 2; ++kh) {
      const int sw = (((kh << 2) | g) ^ r7) << 4;
      bf16x8 af[4], bf[4];
#pragma unroll
      for (int i = 0; i < 4; ++i) {
        af[i] = *(const bf16x8_a*)(Abase + i * 2048 + sw);
        bf[i] = *(const bf16x8_a*)(Bbase + i * 2048 + sw);
      }
#pragma unroll
      for (int i = 0; i < 4; ++i)
#pragma unroll
        for (int j = 0; j < 4; ++j)
          acc[i][j] = __builtin_amdgcn_mfma_f32_16x16x32_bf16(af[i], bf[j],
                                                              acc[i][j], 0, 0, 0);
    }
  }

#pragma unroll
  for (int i = 0; i < 4; ++i)
#pragma unroll
    for (int j = 0; j < 4; ++j)
#pragma unroll
      for (int ri = 0; ri < 4; ++ri)
        C[(size_t)(m0 + wrbase + i * 16 + g * 4 + ri) * QKVN + n0 + wcbase +
          j * 16 + l15] = acc[i][j][ri];
}

// ---------------------------------------------------------------------------
// 2a) prep_q: Qr = bf16(rope(Q) * scale), layout (T, NH*HD) linear.
//     One thread = 8 rope pairs of one (tok, h). fp32 math identical to the
//     round-6 fused path (cos[d]==cos[d+64]).
// ---------------------------------------------------------------------------
__global__ __launch_bounds__(256) void prep_q(const float* __restrict__ qkv,
                                              const float* __restrict__ cosp,
                                              const float* __restrict__ sinp,
                                              __bf16* __restrict__ Qr) {
  const int idx = blockIdx.x * 256 + threadIdx.x;
  const int d0 = (idx & 7) * 8;        // 0..56
  const int hidx = idx >> 3;
  const int h = hidx & (NH - 1);
  const int tok = hidx >> 5;           // 0..T-1
  const float scale = 0.08838834764831845f;

  const float* q = qkv + (size_t)tok * QKVN + h * HD;
  const float* cr = cosp + (size_t)tok * HD + d0;
  const float* sr = sinp + (size_t)tok * HD + d0;
  floatx4 x10 = *(const floatx4_a*)(q + d0);
  floatx4 x11 = *(const floatx4_a*)(q + d0 + 4);
  floatx4 x20 = *(const floatx4_a*)(q + d0 + 64);
  floatx4 x21 = *(const floatx4_a*)(q + d0 + 68);
  floatx4 c0 = *(const floatx4_a*)(cr);
  floatx4 c1 = *(const floatx4_a*)(cr + 4);
  floatx4 s0 = *(const floatx4_a*)(sr);
  floatx4 s1 = *(const floatx4_a*)(sr + 4);
  bf16x8 lo, hi;
#pragma unroll
  for (int e = 0; e < 4; ++e) {
    lo[e] = (__bf16)((x10[e] * c0[e] - x20[e] * s0[e]) * scale);
    lo[e + 4] = (__bf16)((x11[e] * c1[e] - x21[e] * s1[e]) * scale);
    hi[e] = (__bf16)((x20[e] * c0[e] + x10[e] * s0[e]) * scale);
    hi[e + 4] = (__bf16)((x21[e] * c1[e] + x11[e] * s1[e]) * scale);
  }
  __bf16* o = Qr + (size_t)tok * (NH * HD) + h * HD + d0;
  *(bf16x8_a*)(o) = lo;
  *(bf16x8_a*)(o + 64) = hi;
}

// ---------------------------------------------------------------------------
// 2b) prep_kv: per (b, kvh, kt) tile of 64 keys:
//     Kr tile (16 KB): byte L=(key*256 + d*2)^((key&7)<<4) = bf16(rope(K)).
//     Vr tile (16 KB): byte L=(d*128 + key*2)^((d&7)<<4)   = bf16(V) (V^T).
//     Both are EXACT LDS-linear images: attn DMAs them with global_load_lds
//     and reads with the matching XOR (rule #21 pre-swizzled source).
// ---------------------------------------------------------------------------
__global__ __launch_bounds__(256) void prep_kv(const float* __restrict__ qkv,
                                               const float* __restrict__ cosp,
                                               const float* __restrict__ sinp,
                                               char* __restrict__ Kr,
                                               char* __restrict__ Vr) {
  __shared__ __align__(16) __bf16 vls[128][72];  // [d][key], 144B rows
  const int bid = (int)blockIdx.x;
  const int kt = bid & (NKT - 1);
  const int kvh = (bid >> 4) & (NKVH - 1);
  const int b = bid >> 7;
  const int tid = threadIdx.x;
  const int key = tid >> 2;            // 0..63
  const int tok = kt * KVB + key;
  const size_t trow = (size_t)(b * S + tok);
  char* kr_tile = Kr + (size_t)((b * NKVH + kvh) * NKT + kt) * TILE_B;
  char* vr_tile = Vr + (size_t)((b * NKVH + kvh) * NKT + kt) * TILE_B;

  // ---- K: rope + swizzled write. Thread covers d [d0,d0+16) + pair +64.
  {
    const int d0 = (tid & 3) * 16;     // 0,16,32,48
    const float* kp = qkv + trow * QKVN + KOFF + kvh * HD;
    const float* cr = cosp + trow * HD + d0;
    const float* sr = sinp + trow * HD + d0;
    bf16x8 lo[2], hi[2];
#pragma unroll
    for (int m = 0; m < 2; ++m) {
      floatx4 x10 = *(const floatx4_a*)(kp + d0 + m * 8);
      floatx4 x11 = *(const floatx4_a*)(kp + d0 + m * 8 + 4);
      floatx4 x20 = *(const floatx4_a*)(kp + d0 + m * 8 + 64);
      floatx4 x21 = *(const floatx4_a*)(kp + d0 + m * 8 + 68);
      floatx4 c0 = *(const floatx4_a*)(cr + m * 8);
      floatx4 c1 = *(const floatx4_a*)(cr + m * 8 + 4);
      floatx4 s0 = *(const floatx4_a*)(sr + m * 8);
      floatx4 s1 = *(const floatx4_a*)(sr + m * 8 + 4);
#pragma unroll
      for (int e = 0; e < 4; ++e) {
        lo[m][e] = (__bf16)(x10[e] * c0[e] - x20[e] * s0[e]);
        lo[m][e + 4] = (__bf16)(x11[e] * c1[e] - x21[e] * s1[e]);
        hi[m][e] = (__bf16)(x20[e] * c0[e] + x10[e] * s0[e]);
        hi[m][e + 4] = (__bf16)(x21[e] * c1[e] + x11[e] * s1[e]);
      }
    }
    const int swz = (key & 7) << 4;
    const int base = key * 256 + d0 * 2;  // chunk of d0: byte d*2
#pragma unroll
    for (int m = 0; m < 2; ++m) {
      *(bf16x8_a*)(kr_tile + ((base + m * 16) ^ swz)) = lo[m];
      *(bf16x8_a*)(kr_tile + ((base + 128 + m * 16) ^ swz)) = hi[m];
    }
  }

  // ---- V: LDS transpose then swizzled write.
  {
    const int e0 = (tid & 3) * 32;     // 0,32,64,96
    const float* vp = qkv + trow * QKVN + VOFF + kvh * HD;
#pragma unroll
    for (int m = 0; m < 8; ++m) {
      floatx4 v = *(const floatx4_a*)(vp + e0 + m * 4);
#pragma unroll
      for (int e = 0; e < 4; ++e) vls[e0 + m * 4 + e][key] = (__bf16)v[e];
    }
  }
  __syncthreads();
  {
    const int d = tid >> 1;            // 0..127
    const int h2 = tid & 1;            // key half
    const int vswz = (d & 7) << 4;
#pragma unroll
    for (int j = 0; j < 4; ++j) {
      bf16x8 o = *(const bf16x8_a*)(&vls[d][h2 * 32 + j * 8]);
      *(bf16x8_a*)(vr_tile + ((d * 128 + h2 * 64 + j * 16) ^ vswz)) = o;
    }
  }
}

// ---------------------------------------------------------------------------
// 3) Flash attention v2: ZERO in-loop transforms. Per 64-key tile:
//    8 global_load_lds (K 16KB + V^T 16KB, pre-swizzled source) -> barrier ->
//    16 QK MFMA -> in-reg softmax -> P via swizzled LDS -> 16 PV MFMA.
//    4 waves = 4 q-heads sharing K/V; balance remap kept. LDS 40KB ->
//    4 blocks/CU.
// ---------------------------------------------------------------------------
__global__ __launch_bounds__(256) void attn_mfma(
    const __bf16* __restrict__ Qr, const char* __restrict__ Kr,
    const char* __restrict__ Vr, float* __restrict__ out) {
  __shared__ __align__(16) char Ksh[TILE_B];      // 16 KB  [key][d] swizzled
  __shared__ __align__(16) char Vsh[TILE_B];      // 16 KB  [d][key] swizzled
  __shared__ __align__(16) char Psh[4][16 * KVB * 2];  // 2 KB/wave

  const int tid = threadIdx.x;
  const int lane = tid & 63, wave = tid >> 6;
  const int raw = (int)blockIdx.x;
  const int qb_raw = raw & 63;
  const int qb = ((raw >> 8) & 1) ? (63 - qb_raw) : qb_raw;  // balance remap
  const int kvh = (raw >> 6) & 7;
  const int b = raw >> 9;
  const int q0 = qb * 16;
  const int h = kvh * 4 + wave;
  const int NT = (q0 + 79) >> 6;       // 64-key tiles covering keys <= q0+15
  const int l15 = lane & 15, g = lane >> 4;

  // Q fragments: pre-roped, pre-scaled bf16. Straight d-chunks.
  bf16x8 af[4];
  {
    const __bf16* qr = Qr + (size_t)(b * S + q0 + l15) * (NH * HD) + h * HD;
#pragma unroll
    for (int c = 0; c < 4; ++c)
      af[c] = *(const bf16x8_a*)(qr + c * 32 + g * 8);
  }

  floatx4 oacc[8];
#pragma unroll
  for (int i = 0; i < 8; ++i) oacc[i] = (floatx4){0.f, 0.f, 0.f, 0.f};
  float mrow[4], lrow[4], alpha[4];
#pragma unroll
  for (int i = 0; i < 4; ++i) {
    mrow[i] = -__builtin_inff();
    lrow[i] = 0.f;
  }

  const char* kbase = Kr + (size_t)((b * NKVH + kvh) * NKT) * TILE_B;
  const char* vbase = Vr + (size_t)((b * NKVH + kvh) * NKT) * TILE_B;
  char* pb = (char*)Psh[wave];
  const int dmaoff = wave * 1024 + (lane << 4);  // per-lane global offset
  const int ldsoff = wave * 1024;                // wave-uniform LDS base
  const int swz = (l15 & 7) << 4;  // K-read, P-read, V-read all use this form

  for (int kt = 0; kt < NT; ++kt) {
    __syncthreads();  // previous tile's LDS reads complete
    const char* ks = kbase + kt * TILE_B;
    const char* vs = vbase + kt * TILE_B;
#pragma unroll
    for (int j = 0; j < 4; ++j)
      gload_lds16(ks + j * 4096 + dmaoff, Ksh + j * 4096 + ldsoff);
#pragma unroll
    for (int j = 0; j < 4; ++j)
      gload_lds16(vs + j * 4096 + dmaoff, Vsh + j * 4096 + ldsoff);
    __syncthreads();  // vmcnt drained before barrier -> tiles ready

    // ---- QK^T: 4 key-frags x 4 d-chunks. B k-slot == A k-slot (g*8+e).
    floatx4 sa[4];
#pragma unroll
    for (int f = 0; f < 4; ++f) sa[f] = (floatx4){0.f, 0.f, 0.f, 0.f};
#pragma unroll
    for (int c = 0; c < 4; ++c) {
#pragma unroll
      for (int f = 0; f < 4; ++f) {
        // key = f*16 + l15; (key&7)==(l15&7) since f*16 % 8 == 0
        bf16x8 bk = *(const bf16x8_a*)(
            Ksh + (((f * 16 + l15) * 256 + c * 64 + g * 16) ^ swz));
        sa[f] = __builtin_amdgcn_mfma_f32_16x16x32_bf16(af[c], bk, sa[f], 0, 0,
                                                        0);
      }
    }

    // ---- causal mask + online softmax (row = 4g+i, cols across lane group)
    const int kb = kt * KVB;
    float p[4][4];
#pragma unroll
    for (int i = 0; i < 4; ++i) {
      const int qg = q0 + 4 * g + i;
      float s0 = sa[0][i], s1 = sa[1][i], s2 = sa[2][i], s3 = sa[3][i];
      if (kb + l15 > qg) s0 = -3e38f;
      if (kb + 16 + l15 > qg) s1 = -3e38f;
      if (kb + 32 + l15 > qg) s2 = -3e38f;
      if (kb + 48 + l15 > qg) s3 = -3e38f;
      float t = fmaxf(fmaxf(s0, s1), fmaxf(s2, s3));
      t = fmaxf(t, __shfl_xor(t, 1));
      t = fmaxf(t, __shfl_xor(t, 2));
      t = fmaxf(t, __shfl_xor(t, 4));
      t = fmaxf(t, __shfl_xor(t, 8));
      const float mn = fmaxf(mrow[i], t);
      const float al = __expf(mrow[i] - mn);   // first tile: expf(-inf)=0
      const float e0 = __expf(s0 - mn);
      const float e1 = __expf(s1 - mn);
      const float e2 = __expf(s2 - mn);
      const float e3 = __expf(s3 - mn);
      float ps = (e0 + e1) + (e2 + e3);
      ps += __shfl_xor(ps, 1);
      ps += __shfl_xor(ps, 2);
      ps += __shfl_xor(ps, 4);
      ps += __shfl_xor(ps, 8);
      lrow[i] = lrow[i] * al + ps;
      mrow[i] = mn;
      alpha[i] = al;
      p[i][0] = e0; p[i][1] = e1; p[i][2] = e2; p[i][3] = e3;
    }
#pragma unroll
    for (int df = 0; df < 8; ++df)
#pragma unroll
      for (int i = 0; i < 4; ++i) oacc[df][i] *= alpha[i];

    // ---- P -> per-wave LDS [16 rows][64 keys] bf16, XOR'd by (row&7)<<4.
#pragma unroll
    for (int i = 0; i < 4; ++i) {
      const int row = 4 * g + i;
      const int sw = (row & 7) << 4;
#pragma unroll
      for (int f = 0; f < 4; ++f)
        *(bf16_a*)(pb + ((row * 128 + (f * 16 + l15) * 2) ^ sw)) =
            (__bf16)p[i][f];
    }
    // same-wave RAW: compiler inserts lgkmcnt wait; no barrier needed.
    bf16x8 pa0 = *(const bf16x8_a*)(pb + ((l15 * 128 + g * 16) ^ swz));
    bf16x8 pa1 = *(const bf16x8_a*)(pb + ((l15 * 128 + 64 + g * 16) ^ swz));

    // ---- PV: 8 d-frags x 2 k-frags. V^T k-slot == P k-slot.
#pragma unroll
    for (int df = 0; df < 8; ++df) {
      const int d = df * 16 + l15;     // (d&7)==(l15&7)
      bf16x8 v0 = *(const bf16x8_a*)(Vsh + ((d * 128 + g * 16) ^ swz));
      bf16x8 v1 = *(const bf16x8_a*)(Vsh + ((d * 128 + 64 + g * 16) ^ swz));
      oacc[df] =
          __builtin_amdgcn_mfma_f32_16x16x32_bf16(pa0, v0, oacc[df], 0, 0, 0);
      oacc[df] =
          __builtin_amdgcn_mfma_f32_16x16x32_bf16(pa1, v1, oacc[df], 0, 0, 0);
    }
  }

  // ---- epilogue: divide by l, store fp32 (C/D layout col=l15, row=4g+i)
  float* ob = out + (size_t)(b * S + q0) * (NH * HD) + h * HD;
#pragma unroll
  for (int i = 0; i < 4; ++i) {
    const float inv = 1.f / lrow[i];
    const int row = 4 * g + i;
#pragma unroll
    for (int df = 0; df < 8; ++df)
      ob[(size_t)row * (NH * HD) + df * 16 + l15] = oacc[df][i] * inv;
  }
}

// ---------------------------------------------------------------------------
extern "C" void kernel_launch(void* const* d_in, const int* in_sizes, int n_in,
                              void* d_out, int out_size, void* d_ws,
                              size_t ws_size, hipStream_t stream) {
  const float* hidden = (const float*)d_in[0];  // (T, DM)
  const float* w_qkv = (const float*)d_in[1];   // (DM, QKVN)
  const float* cosb = (const float*)d_in[2];    // (T, HD)
  const float* sinb = (const float*)d_in[3];    // (T, HD)
  float* out = (float*)d_out;                   // (T, NH*HD) fp32

  char* ws = (char*)d_ws;
  const size_t qkv_bytes = (size_t)T * QKVN * 4;   // 50.3 MB
  const size_t wt_bytes = (size_t)QKVN * DM * 2;   // 50.3 MB
  // Total requirement unchanged from verified rounds 3/6 (118 MB):
  // prep outputs ALIAS the GEMM's dead staging buffers (stream-ordered).
  float* qkv = (float*)ws;
  __bf16* W16T = (__bf16*)(ws + qkv_bytes);
  __bf16* A16 = (__bf16*)(ws + qkv_bytes + wt_bytes);       // 16.8 MB
  __bf16* Qr = (__bf16*)(ws + qkv_bytes);                   // aliases W16T
  char* Kr = (char*)(ws + qkv_bytes + wt_bytes);            // aliases A16
  char* Vr = Kr + (size_t)B * NKVH * NKT * TILE_B;          // +4 MB (<=16.8)

  convert_a<<<(T * DM) / (256 * 8), 256, 0, stream>>>(hidden, A16);
  transpose_w<<<dim3(DM / 64, QKVN / 64), 256, 0, stream>>>(w_qkv, W16T);
  gemm_mfma<<<dim3(T / 128, QKVN / 128), 256, 0, stream>>>(A16, W16T, qkv);
  // one-time transform pass (rope, scale, bf16, tile-linear swizzled layouts)
  prep_q<<<(T * NH * 8) / 256, 256, 0, stream>>>(qkv, cosb, sinb, Qr);
  prep_kv<<<B * NKVH * NKT, 256, 0, stream>>>(qkv, cosb, sinb, Kr, Vr);
  attn_mfma<<<dim3(B * NKVH * (S / 16)), 256, 0, stream>>>(Qr, Kr, Vr, out);
}

// Round 13
// 395.234 us; speedup vs baseline: 10.9599x; 1.0056x over previous
//
#include <hip/hip_runtime.h>
#include <hip/hip_bf16.h>
#include <stdint.h>

// Problem constants (fixed by setup_inputs)
constexpr int NH   = 32;            // query heads
constexpr int NKVH = 8;             // kv heads
constexpr int HD   = 128;           // head dim
constexpr int DM   = 4096;          // model dim (K of the GEMM)
constexpr int B    = 2;
constexpr int S    = 1024;
constexpr int T    = B * S;         // 2048
constexpr int QKVN = (NH + 2 * NKVH) * HD;  // 6144
constexpr int KOFF = NH * HD;               // 4096 (k section)
constexpr int VOFF = (NH + NKVH) * HD;      // 5120 (v section)
constexpr int KVB  = 64;                    // attn key-tile
constexpr int NKT  = S / KVB;               // 16 tiles per (b,kvh)
constexpr int TILE_B = KVB * HD * 2;        // 16384 bytes per K or V^T tile

typedef float floatx4 __attribute__((ext_vector_type(4)));
typedef floatx4 floatx4_a __attribute__((may_alias));
typedef __bf16 bf16x8 __attribute__((ext_vector_type(8)));
typedef bf16x8 bf16x8_a __attribute__((may_alias));
typedef __bf16 bf16_a __attribute__((may_alias));

__device__ __forceinline__ void gload_lds16(const void* g, void* l) {
  __builtin_amdgcn_global_load_lds(
      (const __attribute__((address_space(1))) void*)g,
      (__attribute__((address_space(3))) void*)l, 16, 0, 0);
}

// ---------------------------------------------------------------------------
// SESSION NOTE (round 13): this is the BYTE-EXACT round-8 source (passed,
// 397.5 us). Bisect across rounds 8-12 showed: split prep kernels pass 3/3;
// merged {prep_inputs, prep_qkv} crash 3/3 (even with this exact attn).
// Merged-prep form is forbidden for this session; keep kernels split.
// ---------------------------------------------------------------------------

// ---------------------------------------------------------------------------
// 0a) hidden (T x DM fp32) -> A16 (T x DM bf16).
// ---------------------------------------------------------------------------
__global__ __launch_bounds__(256) void convert_a(const float* __restrict__ A,
                                                 __bf16* __restrict__ A16) {
  const size_t i = (size_t)(blockIdx.x * 256 + threadIdx.x) * 8;
  floatx4 v0 = *(const floatx4_a*)(A + i);
  floatx4 v1 = *(const floatx4_a*)(A + i + 4);
  bf16x8 o;
#pragma unroll
  for (int e = 0; e < 4; ++e) {
    o[e] = (__bf16)v0[e];
    o[e + 4] = (__bf16)v1[e];
  }
  *(bf16x8_a*)(A16 + i) = o;
}

// ---------------------------------------------------------------------------
// 0b) w_qkv (DM x QKVN fp32) -> W16T (QKVN x DM bf16), K-contiguous B^T.
// ---------------------------------------------------------------------------
__global__ __launch_bounds__(256) void transpose_w(
    const float* __restrict__ W, __bf16* __restrict__ WT) {
  __shared__ __align__(16) __bf16 ls[64][72];
  const int k0 = blockIdx.x * 64;
  const int n0 = blockIdx.y * 64;
  const int tx = threadIdx.x & 15, ty = threadIdx.x >> 4;
#pragma unroll
  for (int rr = 0; rr < 4; ++rr) {
    const int k = ty + rr * 16;
    floatx4 v = *(const floatx4_a*)(W + (size_t)(k0 + k) * QKVN + n0 + tx * 4);
#pragma unroll
    for (int e = 0; e < 4; ++e) ls[tx * 4 + e][k] = (__bf16)v[e];
  }
  __syncthreads();
#pragma unroll
  for (int it = 0; it < 2; ++it) {
    const int n = (threadIdx.x >> 3) + it * 32;
    const int c = threadIdx.x & 7;
    bf16x8 o = *(const bf16x8_a*)(&ls[n][c * 8]);
    *(bf16x8_a*)(WT + (size_t)(n0 + n) * DM + k0 + c * 8) = o;
  }
}

// ---------------------------------------------------------------------------
// 1) GEMM (round-3/8 structure; measured 115 us = m97-structure ceiling,
//    MfmaUtil 41%, 0 bank conflicts).
// ---------------------------------------------------------------------------
__global__ __launch_bounds__(256) void gemm_mfma(
    const __bf16* __restrict__ A16, const __bf16* __restrict__ W16T,
    float* __restrict__ C) {
  __shared__ __align__(16) __bf16 Asig[128 * 64];
  __shared__ __align__(16) __bf16 Bsig[128 * 64];

  const int tid = threadIdx.x;
  const int lane = tid & 63, w = tid >> 6;
  const int l15 = lane & 15, g = lane >> 4;
  const int r7 = l15 & 7;
  const int m0 = blockIdx.x * 128;
  const int n0 = blockIdx.y * 128;
  const int wrbase = (w >> 1) * 64, wcbase = (w & 1) * 64;

  const int srow = tid >> 3;
  const int sce = ((tid & 7) ^ (srow & 7)) << 3;
  const __bf16* agp = A16 + (size_t)(m0 + srow) * DM + sce;
  const __bf16* bgp = W16T + (size_t)(n0 + srow) * DM + sce;
  char* al = (char*)Asig + w * 1024;
  char* bl = (char*)Bsig + w * 1024;

  const char* Abase = (const char*)Asig + (wrbase + l15) * 128;
  const char* Bbase = (const char*)Bsig + (wcbase + l15) * 128;

  floatx4 acc[4][4];
#pragma unroll
  for (int i = 0; i < 4; ++i)
#pragma unroll
    for (int j = 0; j < 4; ++j) acc[i][j] = (floatx4){0.f, 0.f, 0.f, 0.f};

  for (int kk = 0; kk < DM; kk += 64) {
    __syncthreads();
#pragma unroll
    for (int j = 0; j < 4; ++j) {
      gload_lds16(agp + kk + (size_t)(32 * j) * DM, al + j * 4096);
      gload_lds16(bgp + kk + (size_t)(32 * j) * DM, bl + j * 4096);
    }
    __syncthreads();

#pragma unroll
    for (int kh = 0; kh < 2; ++kh) {
      const int sw = (((kh << 2) | g) ^ r7) << 4;
      bf16x8 af[4], bf[4];
#pragma unroll
      for (int i = 0; i < 4; ++i) {
        af[i] = *(const bf16x8_a*)(Abase + i * 2048 + sw);
        bf[i] = *(const bf16x8_a*)(Bbase + i * 2048 + sw);
      }
#pragma unroll
      for (int i = 0; i < 4; ++i)
#pragma unroll
        for (int j = 0; j < 4; ++j)
          acc[i][j] = __builtin_amdgcn_mfma_f32_16x16x32_bf16(af[i], bf[j],
                                                              acc[i][j], 0, 0, 0);
    }
  }

#pragma unroll
  for (int i = 0; i < 4; ++i)
#pragma unroll
    for (int j = 0; j < 4; ++j)
#pragma unroll
      for (int ri = 0; ri < 4; ++ri)
        C[(size_t)(m0 + wrbase + i * 16 + g * 4 + ri) * QKVN + n0 + wcbase +
          j * 16 + l15] = acc[i][j][ri];
}

// ---------------------------------------------------------------------------
// 2a) prep_q: Qr = bf16(rope(Q) * scale), layout (T, NH*HD) linear.
// ---------------------------------------------------------------------------
__global__ __launch_bounds__(256) void prep_q(const float* __restrict__ qkv,
                                              const float* __restrict__ cosp,
                                              const float* __restrict__ sinp,
                                              __bf16* __restrict__ Qr) {
  const int idx = blockIdx.x * 256 + threadIdx.x;
  const int d0 = (idx & 7) * 8;        // 0..56
  const int hidx = idx >> 3;
  const int h = hidx & (NH - 1);
  const int tok = hidx >> 5;           // 0..T-1
  const float scale = 0.08838834764831845f;

  const float* q = qkv + (size_t)tok * QKVN + h * HD;
  const float* cr = cosp + (size_t)tok * HD + d0;
  const float* sr = sinp + (size_t)tok * HD + d0;
  floatx4 x10 = *(const floatx4_a*)(q + d0);
  floatx4 x11 = *(const floatx4_a*)(q + d0 + 4);
  floatx4 x20 = *(const floatx4_a*)(q + d0 + 64);
  floatx4 x21 = *(const floatx4_a*)(q + d0 + 68);
  floatx4 c0 = *(const floatx4_a*)(cr);
  floatx4 c1 = *(const floatx4_a*)(cr + 4);
  floatx4 s0 = *(const floatx4_a*)(sr);
  floatx4 s1 = *(const floatx4_a*)(sr + 4);
  bf16x8 lo, hi;
#pragma unroll
  for (int e = 0; e < 4; ++e) {
    lo[e] = (__bf16)((x10[e] * c0[e] - x20[e] * s0[e]) * scale);
    lo[e + 4] = (__bf16)((x11[e] * c1[e] - x21[e] * s1[e]) * scale);
    hi[e] = (__bf16)((x20[e] * c0[e] + x10[e] * s0[e]) * scale);
    hi[e + 4] = (__bf16)((x21[e] * c1[e] + x11[e] * s1[e]) * scale);
  }
  __bf16* o = Qr + (size_t)tok * (NH * HD) + h * HD + d0;
  *(bf16x8_a*)(o) = lo;
  *(bf16x8_a*)(o + 64) = hi;
}

// ---------------------------------------------------------------------------
// 2b) prep_kv: per (b, kvh, kt) tile of 64 keys:
//     Kr tile (16 KB): byte L=(key*256 + d*2)^((key&7)<<4) = bf16(rope(K)).
//     Vr tile (16 KB): byte L=(d*128 + key*2)^((d&7)<<4)   = bf16(V) (V^T).
//     Both are EXACT LDS-linear images (rule #21 pre-swizzled source).
// ---------------------------------------------------------------------------
__global__ __launch_bounds__(256) void prep_kv(const float* __restrict__ qkv,
                                               const float* __restrict__ cosp,
                                               const float* __restrict__ sinp,
                                               char* __restrict__ Kr,
                                               char* __restrict__ Vr) {
  __shared__ __align__(16) __bf16 vls[128][72];  // [d][key], 144B rows
  const int bid = (int)blockIdx.x;
  const int kt = bid & (NKT - 1);
  const int kvh = (bid >> 4) & (NKVH - 1);
  const int b = bid >> 7;
  const int tid = threadIdx.x;
  const int key = tid >> 2;            // 0..63
  const int tok = kt * KVB + key;
  const size_t trow = (size_t)(b * S + tok);
  char* kr_tile = Kr + (size_t)((b * NKVH + kvh) * NKT + kt) * TILE_B;
  char* vr_tile = Vr + (size_t)((b * NKVH + kvh) * NKT + kt) * TILE_B;

  // ---- K: rope + swizzled write. Thread covers d [d0,d0+16) + pair +64.
  {
    const int d0 = (tid & 3) * 16;     // 0,16,32,48
    const float* kp = qkv + trow * QKVN + KOFF + kvh * HD;
    const float* cr = cosp + trow * HD + d0;
    const float* sr = sinp + trow * HD + d0;
    bf16x8 lo[2], hi[2];
#pragma unroll
    for (int m = 0; m < 2; ++m) {
      floatx4 x10 = *(const floatx4_a*)(kp + d0 + m * 8);
      floatx4 x11 = *(const floatx4_a*)(kp + d0 + m * 8 + 4);
      floatx4 x20 = *(const floatx4_a*)(kp + d0 + m * 8 + 64);
      floatx4 x21 = *(const floatx4_a*)(kp + d0 + m * 8 + 68);
      floatx4 c0 = *(const floatx4_a*)(cr + m * 8);
      floatx4 c1 = *(const floatx4_a*)(cr + m * 8 + 4);
      floatx4 s0 = *(const floatx4_a*)(sr + m * 8);
      floatx4 s1 = *(const floatx4_a*)(sr + m * 8 + 4);
#pragma unroll
      for (int e = 0; e < 4; ++e) {
        lo[m][e] = (__bf16)(x10[e] * c0[e] - x20[e] * s0[e]);
        lo[m][e + 4] = (__bf16)(x11[e] * c1[e] - x21[e] * s1[e]);
        hi[m][e] = (__bf16)(x20[e] * c0[e] + x10[e] * s0[e]);
        hi[m][e + 4] = (__bf16)(x21[e] * c1[e] + x11[e] * s1[e]);
      }
    }
    const int swz = (key & 7) << 4;
    const int base = key * 256 + d0 * 2;  // chunk of d0: byte d*2
#pragma unroll
    for (int m = 0; m < 2; ++m) {
      *(bf16x8_a*)(kr_tile + ((base + m * 16) ^ swz)) = lo[m];
      *(bf16x8_a*)(kr_tile + ((base + 128 + m * 16) ^ swz)) = hi[m];
    }
  }

  // ---- V: LDS transpose then swizzled write.
  {
    const int e0 = (tid & 3) * 32;     // 0,32,64,96
    const float* vp = qkv + trow * QKVN + VOFF + kvh * HD;
#pragma unroll
    for (int m = 0; m < 8; ++m) {
      floatx4 v = *(const floatx4_a*)(vp + e0 + m * 4);
#pragma unroll
      for (int e = 0; e < 4; ++e) vls[e0 + m * 4 + e][key] = (__bf16)v[e];
    }
  }
  __syncthreads();
  {
    const int d = tid >> 1;            // 0..127
    const int h2 = tid & 1;            // key half
    const int vswz = (d & 7) << 4;
#pragma unroll
    for (int j = 0; j < 4; ++j) {
      bf16x8 o = *(const bf16x8_a*)(&vls[d][h2 * 32 + j * 8]);
      *(bf16x8_a*)(vr_tile + ((d * 128 + h2 * 64 + j * 16) ^ vswz)) = o;
    }
  }
}

// ---------------------------------------------------------------------------
// 3) Flash attention v2: ZERO in-loop transforms. Per 64-key tile:
//    8 global_load_lds (K 16KB + V^T 16KB, pre-swizzled source) -> barrier ->
//    16 QK MFMA -> in-reg softmax -> P via swizzled LDS -> 16 PV MFMA.
//    4 waves = 4 q-heads sharing K/V; balance remap kept. LDS 40KB.
//    (Double-buffered variants crashed in rounds 9/11 — keep single-buffer.)
// ---------------------------------------------------------------------------
__global__ __launch_bounds__(256) void attn_mfma(
    const __bf16* __restrict__ Qr, const char* __restrict__ Kr,
    const char* __restrict__ Vr, float* __restrict__ out) {
  __shared__ __align__(16) char Ksh[TILE_B];      // 16 KB  [key][d] swizzled
  __shared__ __align__(16) char Vsh[TILE_B];      // 16 KB  [d][key] swizzled
  __shared__ __align__(16) char Psh[4][16 * KVB * 2];  // 2 KB/wave

  const int tid = threadIdx.x;
  const int lane = tid & 63, wave = tid >> 6;
  const int raw = (int)blockIdx.x;
  const int qb_raw = raw & 63;
  const int qb = ((raw >> 8) & 1) ? (63 - qb_raw) : qb_raw;  // balance remap
  const int kvh = (raw >> 6) & 7;
  const int b = raw >> 9;
  const int q0 = qb * 16;
  const int h = kvh * 4 + wave;
  const int NT = (q0 + 79) >> 6;       // 64-key tiles covering keys <= q0+15
  const int l15 = lane & 15, g = lane >> 4;

  // Q fragments: pre-roped, pre-scaled bf16. Straight d-chunks.
  bf16x8 af[4];
  {
    const __bf16* qr = Qr + (size_t)(b * S + q0 + l15) * (NH * HD) + h * HD;
#pragma unroll
    for (int c = 0; c < 4; ++c)
      af[c] = *(const bf16x8_a*)(qr + c * 32 + g * 8);
  }

  floatx4 oacc[8];
#pragma unroll
  for (int i = 0; i < 8; ++i) oacc[i] = (floatx4){0.f, 0.f, 0.f, 0.f};
  float mrow[4], lrow[4], alpha[4];
#pragma unroll
  for (int i = 0; i < 4; ++i) {
    mrow[i] = -__builtin_inff();
    lrow[i] = 0.f;
  }

  const char* kbase = Kr + (size_t)((b * NKVH + kvh) * NKT) * TILE_B;
  const char* vbase = Vr + (size_t)((b * NKVH + kvh) * NKT) * TILE_B;
  char* pb = (char*)Psh[wave];
  const int dmaoff = wave * 1024 + (lane << 4);  // per-lane global offset
  const int ldsoff = wave * 1024;                // wave-uniform LDS base
  const int swz = (l15 & 7) << 4;  // K-read, P-read, V-read all use this form

  for (int kt = 0; kt < NT; ++kt) {
    __syncthreads();  // previous tile's LDS reads complete
    const char* ks = kbase + kt * TILE_B;
    const char* vs = vbase + kt * TILE_B;
#pragma unroll
    for (int j = 0; j < 4; ++j)
      gload_lds16(ks + j * 4096 + dmaoff, Ksh + j * 4096 + ldsoff);
#pragma unroll
    for (int j = 0; j < 4; ++j)
      gload_lds16(vs + j * 4096 + dmaoff, Vsh + j * 4096 + ldsoff);
    __syncthreads();  // vmcnt drained before barrier -> tiles ready

    // ---- QK^T: 4 key-frags x 4 d-chunks. B k-slot == A k-slot (g*8+e).
    floatx4 sa[4];
#pragma unroll
    for (int f = 0; f < 4; ++f) sa[f] = (floatx4){0.f, 0.f, 0.f, 0.f};
#pragma unroll
    for (int c = 0; c < 4; ++c) {
#pragma unroll
      for (int f = 0; f < 4; ++f) {
        // key = f*16 + l15; (key&7)==(l15&7) since f*16 % 8 == 0
        bf16x8 bk = *(const bf16x8_a*)(
            Ksh + (((f * 16 + l15) * 256 + c * 64 + g * 16) ^ swz));
        sa[f] = __builtin_amdgcn_mfma_f32_16x16x32_bf16(af[c], bk, sa[f], 0, 0,
                                                        0);
      }
    }

    // ---- causal mask + online softmax (row = 4g+i, cols across lane group)
    const int kb = kt * KVB;
    float p[4][4];
#pragma unroll
    for (int i = 0; i < 4; ++i) {
      const int qg = q0 + 4 * g + i;
      float s0 = sa[0][i], s1 = sa[1][i], s2 = sa[2][i], s3 = sa[3][i];
      if (kb + l15 > qg) s0 = -3e38f;
      if (kb + 16 + l15 > qg) s1 = -3e38f;
      if (kb + 32 + l15 > qg) s2 = -3e38f;
      if (kb + 48 + l15 > qg) s3 = -3e38f;
      float t = fmaxf(fmaxf(s0, s1), fmaxf(s2, s3));
      t = fmaxf(t, __shfl_xor(t, 1));
      t = fmaxf(t, __shfl_xor(t, 2));
      t = fmaxf(t, __shfl_xor(t, 4));
      t = fmaxf(t, __shfl_xor(t, 8));
      const float mn = fmaxf(mrow[i], t);
      const float al = __expf(mrow[i] - mn);   // first tile: expf(-inf)=0
      const float e0 = __expf(s0 - mn);
      const float e1 = __expf(s1 - mn);
      const float e2 = __expf(s2 - mn);
      const float e3 = __expf(s3 - mn);
      float ps = (e0 + e1) + (e2 + e3);
      ps += __shfl_xor(ps, 1);
      ps += __shfl_xor(ps, 2);
      ps += __shfl_xor(ps, 4);
      ps += __shfl_xor(ps, 8);
      lrow[i] = lrow[i] * al + ps;
      mrow[i] = mn;
      alpha[i] = al;
      p[i][0] = e0; p[i][1] = e1; p[i][2] = e2; p[i][3] = e3;
    }
#pragma unroll
    for (int df = 0; df < 8; ++df)
#pragma unroll
      for (int i = 0; i < 4; ++i) oacc[df][i] *= alpha[i];

    // ---- P -> per-wave LDS [16 rows][64 keys] bf16, XOR'd by (row&7)<<4.
#pragma unroll
    for (int i = 0; i < 4; ++i) {
      const int row = 4 * g + i;
      const int sw = (row & 7) << 4;
#pragma unroll
      for (int f = 0; f < 4; ++f)
        *(bf16_a*)(pb + ((row * 128 + (f * 16 + l15) * 2) ^ sw)) =
            (__bf16)p[i][f];
    }
    // same-wave LDS RAW: compiler inserts lgkmcnt wait; no barrier needed.
    bf16x8 pa0 = *(const bf16x8_a*)(pb + ((l15 * 128 + g * 16) ^ swz));
    bf16x8 pa1 = *(const bf16x8_a*)(pb + ((l15 * 128 + 64 + g * 16) ^ swz));

    // ---- PV: 8 d-frags x 2 k-frags. V^T k-slot == P k-slot.
#pragma unroll
    for (int df = 0; df < 8; ++df) {
      const int d = df * 16 + l15;     // (d&7)==(l15&7)
      bf16x8 v0 = *(const bf16x8_a*)(Vsh + ((d * 128 + g * 16) ^ swz));
      bf16x8 v1 = *(const bf16x8_a*)(Vsh + ((d * 128 + 64 + g * 16) ^ swz));
      oacc[df] =
          __builtin_amdgcn_mfma_f32_16x16x32_bf16(pa0, v0, oacc[df], 0, 0, 0);
      oacc[df] =
          __builtin_amdgcn_mfma_f32_16x16x32_bf16(pa1, v1, oacc[df], 0, 0, 0);
    }
  }

  // ---- epilogue: divide by l, store fp32 (C/D layout col=l15, row=4g+i)
  float* ob = out + (size_t)(b * S + q0) * (NH * HD) + h * HD;
#pragma unroll
  for (int i = 0; i < 4; ++i) {
    const float inv = 1.f / lrow[i];
    const int row = 4 * g + i;
#pragma unroll
    for (int df = 0; df < 8; ++df)
      ob[(size_t)row * (NH * HD) + df * 16 + l15] = oacc[df][i] * inv;
  }
}

// ---------------------------------------------------------------------------
extern "C" void kernel_launch(void* const* d_in, const int* in_sizes, int n_in,
                              void* d_out, int out_size, void* d_ws,
                              size_t ws_size, hipStream_t stream) {
  const float* hidden = (const float*)d_in[0];  // (T, DM)
  const float* w_qkv = (const float*)d_in[1];   // (DM, QKVN)
  const float* cosb = (const float*)d_in[2];    // (T, HD)
  const float* sinb = (const float*)d_in[3];    // (T, HD)
  float* out = (float*)d_out;                   // (T, NH*HD) fp32

  char* ws = (char*)d_ws;
  const size_t qkv_bytes = (size_t)T * QKVN * 4;   // 50.3 MB
  const size_t wt_bytes = (size_t)QKVN * DM * 2;   // 50.3 MB
  // Total requirement unchanged from verified rounds 3/6/8 (118 MB):
  // prep outputs ALIAS the GEMM's dead staging buffers (stream-ordered).
  float* qkv = (float*)ws;
  __bf16* W16T = (__bf16*)(ws + qkv_bytes);
  __bf16* A16 = (__bf16*)(ws + qkv_bytes + wt_bytes);       // 16.8 MB
  __bf16* Qr = (__bf16*)(ws + qkv_bytes);                   // aliases W16T
  char* Kr = (char*)(ws + qkv_bytes + wt_bytes);            // aliases A16
  char* Vr = Kr + (size_t)B * NKVH * NKT * TILE_B;          // +4 MB (<=16.8)

  convert_a<<<(T * DM) / (256 * 8), 256, 0, stream>>>(hidden, A16);
  transpose_w<<<dim3(DM / 64, QKVN / 64), 256, 0, stream>>>(w_qkv, W16T);
  gemm_mfma<<<dim3(T / 128, QKVN / 128), 256, 0, stream>>>(A16, W16T, qkv);
  // one-time transform pass (rope, scale, bf16, tile-linear swizzled layouts)
  prep_q<<<(T * NH * 8) / 256, 256, 0, stream>>>(qkv, cosb, sinb, Qr);
  prep_kv<<<B * NKVH * NKT, 256, 0, stream>>>(qkv, cosb, sinb, Kr, Vr);
  attn_mfma<<<dim3(B * NKVH * (S / 16)), 256, 0, stream>>>(Qr, Kr, Vr, out);
}